// Round 1
// baseline (1361.765 us; speedup 1.0000x reference)
//
#include <hip/hip_runtime.h>
#include <math.h>

#define NS 256
#define BS 7
#define UU 8
#define NR 4
#define NT 8
#define DD 2
#define HID 200
#define CIN 32
#define PP 100.0f
#define NOISEF 1e-7f

#define HIDP 201   // pad: u*HIDP*2 mod 32 distinct per u -> no LDS bank conflict
#define CINP 33    // pad: u*CINP*2 mod 32 = 2u -> distinct

// ---------------- complex helpers (float2: x=re, y=im) ----------------

// 4x4 complex Hermitian positive-definite solve, 2 RHS, via Cholesky (serial, 1 thread)
__device__ void chol_solve(const float2 (*A)[NR], const float2 (*B)[DD], float2 (*X)[DD]) {
  float2 L[NR][NR];
  for (int j = 0; j < NR; ++j) {
    float d = A[j][j].x;
    for (int k = 0; k < j; ++k) d -= L[j][k].x * L[j][k].x + L[j][k].y * L[j][k].y;
    float ld = sqrtf(fmaxf(d, 1e-30f));
    L[j][j] = make_float2(ld, 0.f);
    float inv = 1.f / ld;
    for (int i = j + 1; i < NR; ++i) {
      float sr = A[i][j].x, si = A[i][j].y;
      for (int k = 0; k < j; ++k) {
        float2 a = L[i][k], b = L[j][k];          // s -= a * conj(b)
        sr -= a.x * b.x + a.y * b.y;
        si -= a.y * b.x - a.x * b.y;
      }
      L[i][j] = make_float2(sr * inv, si * inv);
    }
  }
  for (int c = 0; c < DD; ++c) {
    float2 z[NR];
    for (int i = 0; i < NR; ++i) {                // forward: L z = b
      float sr = B[i][c].x, si = B[i][c].y;
      for (int k = 0; k < i; ++k) {
        float2 a = L[i][k], zz = z[k];            // s -= a * z
        sr -= a.x * zz.x - a.y * zz.y;
        si -= a.x * zz.y + a.y * zz.x;
      }
      float inv = 1.f / L[i][i].x;
      z[i] = make_float2(sr * inv, si * inv);
    }
    for (int i = NR - 1; i >= 0; --i) {           // backward: L^H x = z
      float sr = z[i].x, si = z[i].y;
      for (int k = i + 1; k < NR; ++k) {
        float2 a = L[k][i], xx = X[k][c];         // s -= conj(a) * x
        sr -= a.x * xx.x + a.y * xx.y;
        si -= a.x * xx.y - a.y * xx.x;
      }
      float inv = 1.f / L[i][i].x;
      X[i][c] = make_float2(sr * inv, si * inv);
    }
  }
}

// ---------------- K0: initial power normalization ----------------
__global__ void k_norm0(const float* __restrict__ Vre, const float* __restrict__ Vim,
                        float2* __restrict__ Vcur) {
  int nl = blockIdx.x;          // n*BS + l
  int tid = threadIdx.x;        // 128 threads, one per (u,t,d)
  size_t base = (size_t)nl * (UU * NT * DD);
  float re = Vre[base + tid], im = Vim[base + tid];
  float p = re * re + im * im;
  p += __shfl_down(p, 32); p += __shfl_down(p, 16); p += __shfl_down(p, 8);
  p += __shfl_down(p, 4);  p += __shfl_down(p, 2);  p += __shfl_down(p, 1);
  __shared__ float sred[2];
  if ((tid & 63) == 0) sred[tid >> 6] = p;
  __syncthreads();
  float fro = sred[0] + sred[1];
  float sc = sqrtf(PP / fro);
  Vcur[base + tid] = make_float2(re * sc, im * sc);
}

// ---------------- K1: HV -> Usum/F -> Y, IG   (block per (n,l,i)) ----------------
__global__ __launch_bounds__(64) void k_stage1(const float* __restrict__ Hre,
    const float* __restrict__ Him, const float2* __restrict__ Vcur,
    float2* __restrict__ Yout, float2* __restrict__ IGout) {
  int b = blockIdx.x;                 // (n*BS + l)*U + i
  int i = b % UU; int nl = b / UU; int l = nl % BS; int n = nl / BS;
  int tid = threadIdx.x;

  __shared__ float2 Hs[BS][NR][NT];          // H[n,k,l,i,r,t]
  __shared__ float2 Vs[BS][UU][NT][DD];      // V[n,k,j,t,d]
  __shared__ float2 HV[BS][UU][NR][DD];
  __shared__ float2 Us[NR][NR];
  __shared__ float2 Fs[NR][NR];
  __shared__ float2 HV2s[NR][DD];

  for (int idx = tid; idx < BS * NR * NT; idx += 64) {
    int t = idx & 7, r = (idx >> 3) & 3, k = idx >> 5;
    size_t off = ((((size_t)(n * BS + k)) * BS + l) * UU + i) * (NR * NT) + r * NT + t;
    Hs[k][r][t] = make_float2(Hre[off], Him[off]);
  }
  const float2* Vn = Vcur + (size_t)n * (BS * UU * NT * DD);
  for (int idx = tid; idx < BS * UU * NT * DD; idx += 64)
    ((float2*)Vs)[idx] = Vn[idx];
  __syncthreads();

  // HV[k][j][r][d] = sum_t H[k,r,t] * V[k,j,t,d]
  for (int idx = tid; idx < BS * UU * NR * DD; idx += 64) {
    int d = idx & 1, r = (idx >> 1) & 3, j = (idx >> 3) & 7, k = idx >> 6;
    float ar = 0.f, ai = 0.f;
    #pragma unroll
    for (int t = 0; t < NT; ++t) {
      float2 h = Hs[k][r][t], v = Vs[k][j][t][d];
      ar += h.x * v.x - h.y * v.y;
      ai += h.x * v.y + h.y * v.x;
    }
    HV[k][j][r][d] = make_float2(ar, ai);
  }
  __syncthreads();

  if (tid < NR * DD) {
    int d = tid & 1, r = tid >> 1;
    HV2s[r][d] = HV[l][i][r][d];
  }
  if (tid < NR * NR) {
    int s = tid & 3, r = tid >> 2;
    float ur = 0.f, ui = 0.f;
    for (int k = 0; k < BS; ++k)
      for (int j = 0; j < UU; ++j)
        #pragma unroll
        for (int d = 0; d < DD; ++d) {
          float2 a = HV[k][j][r][d], c = HV[k][j][s][d];   // a * conj(c)
          ur += a.x * c.x + a.y * c.y;
          ui += a.y * c.x - a.x * c.y;
        }
    float tr = 0.f, ti = 0.f;
    #pragma unroll
    for (int d = 0; d < DD; ++d) {
      float2 a = HV[l][i][r][d], c = HV[l][i][s][d];
      tr += a.x * c.x + a.y * c.y;
      ti += a.y * c.x - a.x * c.y;
    }
    if (r == s) ur += NOISEF;
    Us[r][s] = make_float2(ur, ui);
    Fs[r][s] = make_float2(ur - tr, ui - ti);
  }
  __syncthreads();

  if (tid == 0) {
    float2 Yl[NR][DD], Xl[NR][DD];
    chol_solve(Us, HV2s, Yl);     // Usum Y = HV2
    chol_solve(Fs, HV2s, Xl);     // F X = HV2
    for (int r = 0; r < NR; ++r)
      for (int d = 0; d < DD; ++d)
        Yout[((size_t)b * NR + r) * DD + d] = Yl[r][d];
    for (int d = 0; d < DD; ++d)
      for (int e = 0; e < DD; ++e) {
        float gr = (d == e) ? 1.f : 0.f, gi = 0.f;   // IG = I + HV2^H X
        for (int r = 0; r < NR; ++r) {
          float2 a = HV2s[r][d], x = Xl[r][e];       // conj(a) * x
          gr += a.x * x.x + a.y * x.y;
          gi += a.x * x.y - a.y * x.x;
        }
        IGout[(size_t)b * 4 + d * 2 + e] = make_float2(gr, gi);
      }
  }
}

// ---------------- K2: A, L, Lambda -> Z2   (block per (n,l,u)) ----------------
__global__ __launch_bounds__(64) void k_stage2(const float* __restrict__ Hre,
    const float* __restrict__ Him, const float2* __restrict__ Vcur,
    const float2* __restrict__ Y, const float2* __restrict__ IG,
    const float* __restrict__ w, float2* __restrict__ Z2out) {
  int b = blockIdx.x;                 // (n*BS + l)*U + u
  int u = b % UU; int nl = b / UU; int l = nl % BS; int n = nl / BS;
  int tid = threadIdx.x;

  __shared__ float2 Hs[BS][NR][NT];     // H[n,l,m,u,r,t]
  __shared__ float2 Ys[BS][NR][DD];     // Y[n,m,u,r,d]
  __shared__ float2 IGs[BS][DD][DD];    // IG[n,m,u,d,e]
  __shared__ float2 As[BS][NT][DD];
  __shared__ float2 Ls[NT][NT];
  __shared__ float2 Lam[NT][DD];
  __shared__ float2 Zl[NT][DD];

  for (int idx = tid; idx < BS * NR * NT; idx += 64) {
    int t = idx & 7, r = (idx >> 3) & 3, m = idx >> 5;
    size_t off = ((((size_t)(n * BS + l)) * BS + m) * UU + u) * (NR * NT) + r * NT + t;
    Hs[m][r][t] = make_float2(Hre[off], Him[off]);
  }
  for (int idx = tid; idx < BS * NR * DD; idx += 64) {
    int d = idx & 1, r = (idx >> 1) & 3, m = idx >> 3;
    Ys[m][r][d] = Y[(((size_t)(n * BS + m) * UU + u) * NR + r) * DD + d];
  }
  if (tid < BS * DD * DD) {
    int e = tid & 1, d = (tid >> 1) & 1, m = tid >> 2;
    IGs[m][d][e] = IG[((size_t)(n * BS + m) * UU + u) * 4 + d * 2 + e];
  }
  if (tid < NT * DD) {
    int d = tid & 1, t = tid >> 1;
    Zl[t][d] = Vcur[(((size_t)(n * BS + l) * UU + u) * NT + t) * DD + d];
  }
  __syncthreads();

  // A[m][t][d] = sum_r conj(H[m,r,t]) * Y[m,r,d]
  for (int idx = tid; idx < BS * NT * DD; idx += 64) {
    int d = idx & 1, t = (idx >> 1) & 7, m = idx >> 4;
    float ar = 0.f, ai = 0.f;
    #pragma unroll
    for (int r = 0; r < NR; ++r) {
      float2 h = Hs[m][r][t], y = Ys[m][r][d];    // conj(h) * y
      ar += h.x * y.x + h.y * y.y;
      ai += h.x * y.y - h.y * y.x;
    }
    As[m][t][d] = make_float2(ar, ai);
  }
  __syncthreads();

  float wu = w[u];
  if (tid < NT * NT) {
    int s = tid & 7, t = tid >> 3;
    float lr = 0.f, li = 0.f;
    for (int m = 0; m < BS; ++m) {
      #pragma unroll
      for (int e = 0; e < DD; ++e) {
        float br = 0.f, bi = 0.f;                 // B = sum_d A[m,t,d] * IG[m,d,e]
        #pragma unroll
        for (int d = 0; d < DD; ++d) {
          float2 a = As[m][t][d], g = IGs[m][d][e];
          br += a.x * g.x - a.y * g.y;
          bi += a.x * g.y + a.y * g.x;
        }
        float2 ac = As[m][s][e];                  // B * conj(A[m,s,e])
        lr += br * ac.x + bi * ac.y;
        li += bi * ac.x - br * ac.y;
      }
    }
    Ls[t][s] = make_float2(lr * wu, li * wu);
  }
  if (tid < NT * DD) {
    int e = tid & 1, t = tid >> 1;
    float ar = 0.f, ai = 0.f;
    #pragma unroll
    for (int d = 0; d < DD; ++d) {
      float2 a = As[l][t][d], g = IGs[l][d][e];   // Lam = All * IG(l)
      ar += a.x * g.x - a.y * g.y;
      ai += a.x * g.y + a.y * g.x;
    }
    Lam[t][e] = make_float2(ar * wu, ai * wu);
  }
  __syncthreads();

  if (tid < NT * DD) {
    int d = tid & 1, t = tid >> 1;
    float zr = Lam[t][d].x, zi = Lam[t][d].y;
    #pragma unroll
    for (int s = 0; s < NT; ++s) {
      float2 Lts = Ls[t][s], z = Zl[s][d];
      zr -= Lts.x * z.x - Lts.y * z.y;
      zi -= Lts.x * z.y + Lts.y * z.x;
    }
    Z2out[((size_t)b * NT + t) * DD + d] = make_float2(zr, zi);
  }
}

// ---------------- K3: complex MLP + V update + renorm  (block per (n,l)) ----------------
template<int IN, int INSTRIDE>
__device__ inline void clayer(const float2* x, const float* __restrict__ Wre,
                              const float* __restrict__ Wim,
                              const float* __restrict__ bre, const float* __restrict__ bim,
                              float2* h, int tid) {
  for (int tau = tid; tau < UU * HID; tau += 256) {
    int u = tau & 7, o = tau >> 3;     // 8 lanes share o -> W reads broadcast
    float ar = bre[o], ai = bim[o];
    const float* wr = Wre + o * IN;
    const float* wi = Wim + o * IN;
    const float2* xu = x + u * INSTRIDE;
    #pragma unroll 4
    for (int i2 = 0; i2 < IN; ++i2) {
      float2 xv = xu[i2];
      float wrv = wr[i2], wiv = wi[i2];
      ar = fmaf(xv.x, wrv, ar); ar = fmaf(-xv.y, wiv, ar);
      ai = fmaf(xv.x, wiv, ai); ai = fmaf(xv.y, wrv, ai);
    }
    h[u * HIDP + o] = make_float2(fmaxf(ar, 0.f), ai);   // crelu
  }
}

__global__ __launch_bounds__(256) void k_mlp(const float2* __restrict__ Vcur,
    const float2* __restrict__ Z2,
    const float* __restrict__ W1re, const float* __restrict__ W1im,
    const float* __restrict__ b1re, const float* __restrict__ b1im,
    const float* __restrict__ W2re, const float* __restrict__ W2im,
    const float* __restrict__ b2re, const float* __restrict__ b2im,
    const float* __restrict__ W3re, const float* __restrict__ W3im,
    const float* __restrict__ b3re, const float* __restrict__ b3im,
    const float* __restrict__ W4re, const float* __restrict__ W4im,
    const float* __restrict__ b4re, const float* __restrict__ b4im,
    float2* __restrict__ Vout) {
  int nl = blockIdx.x;
  int tid = threadIdx.x;
  __shared__ float2 xin[UU][CINP];
  __shared__ float2 hb[2][UU][HIDP];
  __shared__ float stepv[UU];
  __shared__ float sred[4];

  const float2* Zp  = Vcur + (size_t)nl * (UU * NT * DD);
  const float2* Z2p = Z2   + (size_t)nl * (UU * NT * DD);
  for (int idx = tid; idx < UU * 16; idx += 256) {
    int u = idx >> 4, ii = idx & 15;
    xin[u][ii]      = Zp[idx];
    xin[u][16 + ii] = Z2p[idx];
  }
  __syncthreads();
  clayer<CIN, CINP>(&xin[0][0], W1re, W1im, b1re, b1im, &hb[0][0][0], tid);
  __syncthreads();
  clayer<HID, HIDP>(&hb[0][0][0], W2re, W2im, b2re, b2im, &hb[1][0][0], tid);
  __syncthreads();
  clayer<HID, HIDP>(&hb[1][0][0], W3re, W3im, b3re, b3im, &hb[0][0][0], tid);
  __syncthreads();

  if (tid < 64) {                       // layer 4: step[u] = Re(h . W4 + b4)
    int u = tid >> 3, seg = tid & 7;
    float acc = 0.f;
    for (int i2 = seg; i2 < HID; i2 += 8) {
      float2 hv = hb[0][u][i2];
      acc += hv.x * W4re[i2] - hv.y * W4im[i2];
    }
    acc += __shfl_down(acc, 4, 8);
    acc += __shfl_down(acc, 2, 8);
    acc += __shfl_down(acc, 1, 8);
    if (seg == 0) stepv[u] = acc + b4re[0];
  }
  __syncthreads();

  float partial = 0.f;
  float2 vn = make_float2(0.f, 0.f);
  if (tid < 128) {
    int u = tid >> 4, ii = tid & 15;
    float2 z = xin[u][ii], z2 = xin[u][16 + ii];
    float st = stepv[u];
    vn = make_float2(fmaf(st, z2.x, z.x), fmaf(st, z2.y, z.y));
    partial = vn.x * vn.x + vn.y * vn.y;
  }
  float p = partial;
  p += __shfl_down(p, 32); p += __shfl_down(p, 16); p += __shfl_down(p, 8);
  p += __shfl_down(p, 4);  p += __shfl_down(p, 2);  p += __shfl_down(p, 1);
  if ((tid & 63) == 0) sred[tid >> 6] = p;
  __syncthreads();
  float fro = sred[0] + sred[1] + sred[2] + sred[3];
  float sc = (fro > PP) ? sqrtf(PP / fro) : 1.0f;
  if (tid < 128) Vout[(size_t)nl * 128 + tid] = make_float2(vn.x * sc, vn.y * sc);
}

// ---------------- launch ----------------
extern "C" void kernel_launch(void* const* d_in, const int* in_sizes, int n_in,
                              void* d_out, int out_size, void* d_ws, size_t ws_size,
                              hipStream_t stream) {
  const float* Hre  = (const float*)d_in[0];
  const float* Him  = (const float*)d_in[1];
  const float* Vre  = (const float*)d_in[2];
  const float* Vim  = (const float*)d_in[3];
  const float* w    = (const float*)d_in[4];
  const float* W1re = (const float*)d_in[5];
  const float* W1im = (const float*)d_in[6];
  const float* b1re = (const float*)d_in[7];
  const float* b1im = (const float*)d_in[8];
  const float* W2re = (const float*)d_in[9];
  const float* W2im = (const float*)d_in[10];
  const float* b2re = (const float*)d_in[11];
  const float* b2im = (const float*)d_in[12];
  const float* W3re = (const float*)d_in[13];
  const float* W3im = (const float*)d_in[14];
  const float* b3re = (const float*)d_in[15];
  const float* b3im = (const float*)d_in[16];
  const float* W4re = (const float*)d_in[17];
  const float* W4im = (const float*)d_in[18];
  const float* b4re = (const float*)d_in[19];
  const float* b4im = (const float*)d_in[20];

  const size_t NV = (size_t)NS * BS * UU * NT * DD;   // 229376 complex
  float2* Vcur = (float2*)d_ws;
  float2* Z2b  = Vcur + NV;
  float2* Yb   = Z2b + NV;
  float2* IGb  = Yb + (size_t)NS * BS * UU * NR * DD;

  k_norm0<<<NS * BS, 128, 0, stream>>>(Vre, Vim, Vcur);
  for (int it = 0; it < 3; ++it) {
    k_stage1<<<NS * BS * UU, 64, 0, stream>>>(Hre, Him, Vcur, Yb, IGb);
    k_stage2<<<NS * BS * UU, 64, 0, stream>>>(Hre, Him, Vcur, Yb, IGb, w, Z2b);
    float2* vout = (it == 2) ? (float2*)d_out : Vcur;
    k_mlp<<<NS * BS, 256, 0, stream>>>(Vcur, Z2b,
        W1re + it * HID * CIN, W1im + it * HID * CIN, b1re + it * HID, b1im + it * HID,
        W2re + it * HID * HID, W2im + it * HID * HID, b2re + it * HID, b2im + it * HID,
        W3re + it * HID * HID, W3im + it * HID * HID, b3re + it * HID, b3im + it * HID,
        W4re + it * HID, W4im + it * HID, b4re + it, b4im + it,
        vout);
  }
}

// Round 2
// 425.459 us; speedup vs baseline: 3.2007x; 3.2007x over previous
//
#include <hip/hip_runtime.h>
#include <math.h>

#define NS 256
#define BS 7
#define UU 8
#define NR 4
#define NT 8
#define DD 2
#define HID 200
#define CIN 32
#define PP 100.0f
#define NOISEF 1e-7f

typedef _Float16 f16x8 __attribute__((ext_vector_type(8)));
typedef float f32x4 __attribute__((ext_vector_type(4)));

#define AST 424      // big activation buffer row stride (halves): 848B = 53x16B (odd -> conflict-free)
#define AST0 104     // layer-1 input stride (halves): 208B = 13x16B (odd)
#define NTILES 28    // 448 output cols = 2*200 valid + pad
#define B1_KC 3      // layer1 K' = 96 (32 re + 32 im + bias + pad)
#define B23_KC 13    // layers2/3 K' = 416 (200 re + pad + bias + 200 im + pad)
#define B1_HALVES (B1_KC*NTILES*64*8)
#define B23_HALVES (B23_KC*NTILES*64*8)
#define BITER_HALVES (B1_HALVES + 2*B23_HALVES)

// ---------------- complex helpers ----------------
__device__ void chol_solve(const float2 (*A)[NR], const float2 (*B)[DD], float2 (*X)[DD]) {
  float2 L[NR][NR];
  for (int j = 0; j < NR; ++j) {
    float d = A[j][j].x;
    for (int k = 0; k < j; ++k) d -= L[j][k].x * L[j][k].x + L[j][k].y * L[j][k].y;
    float ld = sqrtf(fmaxf(d, 1e-30f));
    L[j][j] = make_float2(ld, 0.f);
    float inv = 1.f / ld;
    for (int i = j + 1; i < NR; ++i) {
      float sr = A[i][j].x, si = A[i][j].y;
      for (int k = 0; k < j; ++k) {
        float2 a = L[i][k], b = L[j][k];
        sr -= a.x * b.x + a.y * b.y;
        si -= a.y * b.x - a.x * b.y;
      }
      L[i][j] = make_float2(sr * inv, si * inv);
    }
  }
  for (int c = 0; c < DD; ++c) {
    float2 z[NR];
    for (int i = 0; i < NR; ++i) {
      float sr = B[i][c].x, si = B[i][c].y;
      for (int k = 0; k < i; ++k) {
        float2 a = L[i][k], zz = z[k];
        sr -= a.x * zz.x - a.y * zz.y;
        si -= a.x * zz.y + a.y * zz.x;
      }
      float inv = 1.f / L[i][i].x;
      z[i] = make_float2(sr * inv, si * inv);
    }
    for (int i = NR - 1; i >= 0; --i) {
      float sr = z[i].x, si = z[i].y;
      for (int k = i + 1; k < NR; ++k) {
        float2 a = L[k][i], xx = X[k][c];
        sr -= a.x * xx.x + a.y * xx.y;
        si -= a.x * xx.y - a.y * xx.x;
      }
      float inv = 1.f / L[i][i].x;
      X[i][c] = make_float2(sr * inv, si * inv);
    }
  }
}

// ---------------- K0: initial power normalization ----------------
__global__ void k_norm0(const float* __restrict__ Vre, const float* __restrict__ Vim,
                        float2* __restrict__ Vcur) {
  int nl = blockIdx.x;
  int tid = threadIdx.x;
  size_t base = (size_t)nl * (UU * NT * DD);
  float re = Vre[base + tid], im = Vim[base + tid];
  float p = re * re + im * im;
  p += __shfl_down(p, 32); p += __shfl_down(p, 16); p += __shfl_down(p, 8);
  p += __shfl_down(p, 4);  p += __shfl_down(p, 2);  p += __shfl_down(p, 1);
  __shared__ float sred[2];
  if ((tid & 63) == 0) sred[tid >> 6] = p;
  __syncthreads();
  float fro = sred[0] + sred[1];
  float sc = sqrtf(PP / fro);
  Vcur[base + tid] = make_float2(re * sc, im * sc);
}

// ---------------- K1: HV -> Usum/F -> Y, IG ----------------
__global__ __launch_bounds__(64) void k_stage1(const float* __restrict__ Hre,
    const float* __restrict__ Him, const float2* __restrict__ Vcur,
    float2* __restrict__ Yout, float2* __restrict__ IGout) {
  int b = blockIdx.x;
  int i = b % UU; int nl = b / UU; int l = nl % BS; int n = nl / BS;
  int tid = threadIdx.x;

  __shared__ float2 Hs[BS][NR][NT];
  __shared__ float2 Vs[BS][UU][NT][DD];
  __shared__ float2 HV[BS][UU][NR][DD];
  __shared__ float2 Us[NR][NR];
  __shared__ float2 Fs[NR][NR];
  __shared__ float2 HV2s[NR][DD];

  for (int idx = tid; idx < BS * NR * NT; idx += 64) {
    int t = idx & 7, r = (idx >> 3) & 3, k = idx >> 5;
    size_t off = ((((size_t)(n * BS + k)) * BS + l) * UU + i) * (NR * NT) + r * NT + t;
    Hs[k][r][t] = make_float2(Hre[off], Him[off]);
  }
  const float2* Vn = Vcur + (size_t)n * (BS * UU * NT * DD);
  for (int idx = tid; idx < BS * UU * NT * DD; idx += 64)
    ((float2*)Vs)[idx] = Vn[idx];
  __syncthreads();

  for (int idx = tid; idx < BS * UU * NR * DD; idx += 64) {
    int d = idx & 1, r = (idx >> 1) & 3, j = (idx >> 3) & 7, k = idx >> 6;
    float ar = 0.f, ai = 0.f;
    #pragma unroll
    for (int t = 0; t < NT; ++t) {
      float2 h = Hs[k][r][t], v = Vs[k][j][t][d];
      ar += h.x * v.x - h.y * v.y;
      ai += h.x * v.y + h.y * v.x;
    }
    HV[k][j][r][d] = make_float2(ar, ai);
  }
  __syncthreads();

  if (tid < NR * DD) {
    int d = tid & 1, r = tid >> 1;
    HV2s[r][d] = HV[l][i][r][d];
  }
  if (tid < NR * NR) {
    int s = tid & 3, r = tid >> 2;
    float ur = 0.f, ui = 0.f;
    for (int k = 0; k < BS; ++k)
      for (int j = 0; j < UU; ++j)
        #pragma unroll
        for (int d = 0; d < DD; ++d) {
          float2 a = HV[k][j][r][d], c = HV[k][j][s][d];
          ur += a.x * c.x + a.y * c.y;
          ui += a.y * c.x - a.x * c.y;
        }
    float tr = 0.f, ti = 0.f;
    #pragma unroll
    for (int d = 0; d < DD; ++d) {
      float2 a = HV[l][i][r][d], c = HV[l][i][s][d];
      tr += a.x * c.x + a.y * c.y;
      ti += a.y * c.x - a.x * c.y;
    }
    if (r == s) ur += NOISEF;
    Us[r][s] = make_float2(ur, ui);
    Fs[r][s] = make_float2(ur - tr, ui - ti);
  }
  __syncthreads();

  if (tid == 0) {
    float2 Yl[NR][DD], Xl[NR][DD];
    chol_solve(Us, HV2s, Yl);
    chol_solve(Fs, HV2s, Xl);
    for (int r = 0; r < NR; ++r)
      for (int d = 0; d < DD; ++d)
        Yout[((size_t)b * NR + r) * DD + d] = Yl[r][d];
    for (int d = 0; d < DD; ++d)
      for (int e = 0; e < DD; ++e) {
        float gr = (d == e) ? 1.f : 0.f, gi = 0.f;
        for (int r = 0; r < NR; ++r) {
          float2 a = HV2s[r][d], x = Xl[r][e];
          gr += a.x * x.x + a.y * x.y;
          gi += a.x * x.y - a.y * x.x;
        }
        IGout[(size_t)b * 4 + d * 2 + e] = make_float2(gr, gi);
      }
  }
}

// ---------------- K2: A, L, Lambda -> Z2 ----------------
__global__ __launch_bounds__(64) void k_stage2(const float* __restrict__ Hre,
    const float* __restrict__ Him, const float2* __restrict__ Vcur,
    const float2* __restrict__ Y, const float2* __restrict__ IG,
    const float* __restrict__ w, float2* __restrict__ Z2out) {
  int b = blockIdx.x;
  int u = b % UU; int nl = b / UU; int l = nl % BS; int n = nl / BS;
  int tid = threadIdx.x;

  __shared__ float2 Hs[BS][NR][NT];
  __shared__ float2 Ys[BS][NR][DD];
  __shared__ float2 IGs[BS][DD][DD];
  __shared__ float2 As[BS][NT][DD];
  __shared__ float2 Ls[NT][NT];
  __shared__ float2 Lam[NT][DD];
  __shared__ float2 Zl[NT][DD];

  for (int idx = tid; idx < BS * NR * NT; idx += 64) {
    int t = idx & 7, r = (idx >> 3) & 3, m = idx >> 5;
    size_t off = ((((size_t)(n * BS + l)) * BS + m) * UU + u) * (NR * NT) + r * NT + t;
    Hs[m][r][t] = make_float2(Hre[off], Him[off]);
  }
  for (int idx = tid; idx < BS * NR * DD; idx += 64) {
    int d = idx & 1, r = (idx >> 1) & 3, m = idx >> 3;
    Ys[m][r][d] = Y[(((size_t)(n * BS + m) * UU + u) * NR + r) * DD + d];
  }
  if (tid < BS * DD * DD) {
    int e = tid & 1, d = (tid >> 1) & 1, m = tid >> 2;
    IGs[m][d][e] = IG[((size_t)(n * BS + m) * UU + u) * 4 + d * 2 + e];
  }
  if (tid < NT * DD) {
    int d = tid & 1, t = tid >> 1;
    Zl[t][d] = Vcur[(((size_t)(n * BS + l) * UU + u) * NT + t) * DD + d];
  }
  __syncthreads();

  for (int idx = tid; idx < BS * NT * DD; idx += 64) {
    int d = idx & 1, t = (idx >> 1) & 7, m = idx >> 4;
    float ar = 0.f, ai = 0.f;
    #pragma unroll
    for (int r = 0; r < NR; ++r) {
      float2 h = Hs[m][r][t], y = Ys[m][r][d];
      ar += h.x * y.x + h.y * y.y;
      ai += h.x * y.y - h.y * y.x;
    }
    As[m][t][d] = make_float2(ar, ai);
  }
  __syncthreads();

  float wu = w[u];
  if (tid < NT * NT) {
    int s = tid & 7, t = tid >> 3;
    float lr = 0.f, li = 0.f;
    for (int m = 0; m < BS; ++m) {
      #pragma unroll
      for (int e = 0; e < DD; ++e) {
        float br = 0.f, bi = 0.f;
        #pragma unroll
        for (int d = 0; d < DD; ++d) {
          float2 a = As[m][t][d], g = IGs[m][d][e];
          br += a.x * g.x - a.y * g.y;
          bi += a.x * g.y + a.y * g.x;
        }
        float2 ac = As[m][s][e];
        lr += br * ac.x + bi * ac.y;
        li += bi * ac.x - br * ac.y;
      }
    }
    Ls[t][s] = make_float2(lr * wu, li * wu);
  }
  if (tid < NT * DD) {
    int e = tid & 1, t = tid >> 1;
    float ar = 0.f, ai = 0.f;
    #pragma unroll
    for (int d = 0; d < DD; ++d) {
      float2 a = As[l][t][d], g = IGs[l][d][e];
      ar += a.x * g.x - a.y * g.y;
      ai += a.x * g.y + a.y * g.x;
    }
    Lam[t][e] = make_float2(ar * wu, ai * wu);
  }
  __syncthreads();

  if (tid < NT * DD) {
    int d = tid & 1, t = tid >> 1;
    float zr = Lam[t][d].x, zi = Lam[t][d].y;
    #pragma unroll
    for (int s = 0; s < NT; ++s) {
      float2 Lts = Ls[t][s], z = Zl[s][d];
      zr -= Lts.x * z.x - Lts.y * z.y;
      zi -= Lts.x * z.y + Lts.y * z.x;
    }
    Z2out[((size_t)b * NT + t) * DD + d] = make_float2(zr, zi);
  }
}

// ---------------- Bpack: weights -> fragment-major fp16 real-GEMM form ----------------
// Real B per layer: rows = [xr-part | (pad,bias) | xi-part | pad], cols = interleaved (re,im) outputs.
__global__ __launch_bounds__(256) void k_pack(
    const float* __restrict__ W1re, const float* __restrict__ W1im,
    const float* __restrict__ b1re, const float* __restrict__ b1im,
    const float* __restrict__ W2re, const float* __restrict__ W2im,
    const float* __restrict__ b2re, const float* __restrict__ b2im,
    const float* __restrict__ W3re, const float* __restrict__ W3im,
    const float* __restrict__ b3re, const float* __restrict__ b3im,
    _Float16* __restrict__ Bout) {
  int gid = blockIdx.x * 256 + threadIdx.x;
  int lane = gid & 63;
  int rest = gid >> 6;
  int nt = rest % NTILES;
  int id2 = rest / NTILES;
  if (id2 >= 87) return;
  int iter = id2 / 29, kk = id2 % 29;
  int layer, kc;
  if (kk < 3)       { layer = 0; kc = kk; }
  else if (kk < 16) { layer = 1; kc = kk - 3; }
  else              { layer = 2; kc = kk - 16; }
  const float *Wr, *Wi, *br, *bi;
  if (layer == 0) { Wr = W1re + iter*HID*CIN; Wi = W1im + iter*HID*CIN; br = b1re + iter*HID; bi = b1im + iter*HID; }
  else if (layer == 1) { Wr = W2re + iter*HID*HID; Wi = W2im + iter*HID*HID; br = b2re + iter*HID; bi = b2im + iter*HID; }
  else { Wr = W3re + iter*HID*HID; Wi = W3im + iter*HID*HID; br = b3re + iter*HID; bi = b3im + iter*HID; }
  int c = nt * 16 + (lane & 15);
  int o = c >> 1; int odd = c & 1;
  f16x8 frag;
  #pragma unroll
  for (int j = 0; j < 8; ++j) {
    int k = kc * 32 + (lane >> 4) * 8 + j;
    float v = 0.f;
    if (o < HID) {
      if (layer == 0) {
        if (k < 32)       v = odd ? Wi[o*32 + k] : Wr[o*32 + k];
        else if (k < 64)  { int i = k - 32; v = odd ? Wr[o*32 + i] : -Wi[o*32 + i]; }
        else if (k == 64) v = odd ? bi[o] : br[o];
      } else {
        if (k < 200)       v = odd ? Wi[o*200 + k] : Wr[o*200 + k];
        else if (k == 207) v = odd ? bi[o] : br[o];
        else if (k >= 208 && k < 408) { int i = k - 208; v = odd ? Wr[o*200 + i] : -Wi[o*200 + i]; }
      }
    }
    frag[j] = (_Float16)v;
  }
  size_t off = (size_t)iter * BITER_HALVES
             + (layer == 0 ? 0 : (layer == 1 ? B1_HALVES : (B1_HALVES + B23_HALVES)))
             + ((size_t)(kc * NTILES + nt) * 64 + lane) * 8;
  *(f16x8*)(Bout + off) = frag;
}

// ---------------- fused MFMA MLP ----------------
// A-frag: a[j] = A[lane&15][8*(lane>>4)+j]; B-frag: b[j] = B[8*(lane>>4)+j][lane&15]
// C/D:    d[q] = D[(lane>>4)*4+q][lane&15]   (m89-verified layout)
template<int ASTRIDE>
__device__ inline void do_gemm(const _Float16* Ain, int KC,
                               const _Float16* __restrict__ Bg,
                               _Float16* Aout, int wave, int lane) {
  f32x4 acc[4][7];
  #pragma unroll
  for (int rt = 0; rt < 4; ++rt)
    #pragma unroll
    for (int nt = 0; nt < 7; ++nt)
      acc[rt][nt] = (f32x4){0.f, 0.f, 0.f, 0.f};
  const int r0 = lane & 15, g = lane >> 4;
  #pragma unroll 2
  for (int kc = 0; kc < KC; ++kc) {
    f16x8 a0 = *(const f16x8*)(Ain + (r0 +  0) * ASTRIDE + kc * 32 + 8 * g);
    f16x8 a1 = *(const f16x8*)(Ain + (r0 + 16) * ASTRIDE + kc * 32 + 8 * g);
    f16x8 a2 = *(const f16x8*)(Ain + (r0 + 32) * ASTRIDE + kc * 32 + 8 * g);
    f16x8 a3 = *(const f16x8*)(Ain + (r0 + 48) * ASTRIDE + kc * 32 + 8 * g);
    const _Float16* bp = Bg + ((size_t)(kc * NTILES + wave * 7) * 64 + lane) * 8;
    #pragma unroll
    for (int nt = 0; nt < 7; ++nt) {
      f16x8 b = *(const f16x8*)(bp + nt * 64 * 8);
      acc[0][nt] = __builtin_amdgcn_mfma_f32_16x16x32_f16(a0, b, acc[0][nt], 0, 0, 0);
      acc[1][nt] = __builtin_amdgcn_mfma_f32_16x16x32_f16(a1, b, acc[1][nt], 0, 0, 0);
      acc[2][nt] = __builtin_amdgcn_mfma_f32_16x16x32_f16(a2, b, acc[2][nt], 0, 0, 0);
      acc[3][nt] = __builtin_amdgcn_mfma_f32_16x16x32_f16(a3, b, acc[3][nt], 0, 0, 0);
    }
  }
  // epilogue: crelu (relu on re, pass im), fp16, store to Aout (stride AST)
  int cbase = wave * 7 * 16 + r0;
  #pragma unroll
  for (int nt = 0; nt < 7; ++nt) {
    int c = cbase + nt * 16;
    int o = c >> 1;
    bool isre = !(c & 1);
    if (o < HID) {
      _Float16* outp = Aout + (isre ? o : 208 + o);
      #pragma unroll
      for (int rt = 0; rt < 4; ++rt)
        #pragma unroll
        for (int q = 0; q < 4; ++q) {
          float v = acc[rt][nt][q];
          if (isre) v = fmaxf(v, 0.f);
          outp[(size_t)(rt * 16 + g * 4 + q) * AST] = (_Float16)v;
        }
    }
  }
}

__global__ __launch_bounds__(256, 1) void k_mlp_mfma(
    const float2* __restrict__ Vcur, const float2* __restrict__ Z2,
    const _Float16* __restrict__ Bp,
    const float* __restrict__ W4re, const float* __restrict__ W4im,
    const float* __restrict__ b4re,
    float2* __restrict__ Vout) {
  int b = blockIdx.x;        // owns 8 nl = 64 MLP rows
  int tid = threadIdx.x;
  int wave = tid >> 6, lane = tid & 63;

  __shared__ _Float16 A0[64 * AST0];
  __shared__ _Float16 Abuf[2][64 * AST];
  __shared__ float2 Zs[64][16];
  __shared__ float2 Z2s[64][16];
  __shared__ float w4s[2][HID];
  __shared__ float stepv[64];
  __shared__ float scs[8];

  // load Z, Z2 (each row: 16 complex)
  for (int idx = tid; idx < 1024; idx += 256) {
    ((float2*)Zs)[idx]  = Vcur[(size_t)b * 1024 + idx];
    ((float2*)Z2s)[idx] = Z2[(size_t)b * 1024 + idx];
  }
  for (int idx = tid; idx < HID; idx += 256) {
    w4s[0][idx] = W4re[idx];
    w4s[1][idx] = W4im[idx];
  }
  __syncthreads();

  // build A0: [xr(32) | xi(32) | 1 | 0...]  where x = concat(Z16, Z2_16)
  for (int idx = tid; idx < 64 * AST0; idx += 256) {
    int m = idx / AST0, c = idx % AST0;
    float v;
    if (c < 64) {
      int f = c & 31;
      float2 z = (f < 16) ? Zs[m][f] : Z2s[m][f - 16];
      v = (c >= 32) ? z.y : z.x;
    } else v = (c == 64) ? 1.f : 0.f;
    A0[m * AST0 + c] = (_Float16)v;
  }
  // init pad/bias cols of both big buffers: cols 200..207 = {0..0,1}, 408..415 = 0
  for (int idx = tid; idx < 2 * 64 * 16; idx += 256) {
    int buf = idx >> 10, rem = idx & 1023, m = rem >> 4, p = rem & 15;
    int c = (p < 8) ? (200 + p) : (400 + p);
    Abuf[buf][m * AST + c] = (p == 7) ? (_Float16)1.f : (_Float16)0.f;
  }
  __syncthreads();

  do_gemm<AST0>(A0, B1_KC, Bp, &Abuf[0][0], wave, lane);
  __syncthreads();
  do_gemm<AST>(&Abuf[0][0], B23_KC, Bp + B1_HALVES, &Abuf[1][0], wave, lane);
  __syncthreads();
  do_gemm<AST>(&Abuf[1][0], B23_KC, Bp + B1_HALVES + B23_HALVES, &Abuf[0][0], wave, lane);
  __syncthreads();

  // layer 4: step[m] = Re(h . W4) + b4re
  {
    int m = tid >> 2, q = tid & 3;
    float acc = 0.f;
    for (int o = q; o < HID; o += 4) {
      float hr = (float)Abuf[0][m * AST + o];
      float hi = (float)Abuf[0][m * AST + 208 + o];
      acc += hr * w4s[0][o] - hi * w4s[1][o];
    }
    acc += __shfl_down(acc, 2);
    acc += __shfl_down(acc, 1);
    if (q == 0) stepv[m] = acc + b4re[0];
  }
  __syncthreads();

  // Vn = Z + step * Z2 (in place into Zs)
  for (int idx = tid; idx < 1024; idx += 256) {
    int m = idx >> 4, f = idx & 15;
    float st = stepv[m];
    float2 z = Zs[m][f], z2 = Z2s[m][f];
    Zs[m][f] = make_float2(fmaf(st, z2.x, z.x), fmaf(st, z2.y, z.y));
  }
  __syncthreads();

  // per-nl renorm (8 nl per block, wave handles 2)
  for (int h = 0; h < 2; ++h) {
    int nl = wave * 2 + h;
    const float2* vp = &Zs[nl * 8][0];
    float2 v0 = vp[lane * 2], v1 = vp[lane * 2 + 1];
    float p = v0.x * v0.x + v0.y * v0.y + v1.x * v1.x + v1.y * v1.y;
    p += __shfl_down(p, 32); p += __shfl_down(p, 16); p += __shfl_down(p, 8);
    p += __shfl_down(p, 4);  p += __shfl_down(p, 2);  p += __shfl_down(p, 1);
    if (lane == 0) {
      float fro = p;
      scs[nl] = (fro > PP) ? sqrtf(PP / fro) : 1.f;
    }
  }
  __syncthreads();
  for (int idx = tid; idx < 1024; idx += 256) {
    float sc = scs[idx >> 7];
    float2 v = ((float2*)Zs)[idx];
    Vout[(size_t)b * 1024 + idx] = make_float2(v.x * sc, v.y * sc);
  }
}

// ---------------- launch ----------------
extern "C" void kernel_launch(void* const* d_in, const int* in_sizes, int n_in,
                              void* d_out, int out_size, void* d_ws, size_t ws_size,
                              hipStream_t stream) {
  const float* Hre  = (const float*)d_in[0];
  const float* Him  = (const float*)d_in[1];
  const float* Vre  = (const float*)d_in[2];
  const float* Vim  = (const float*)d_in[3];
  const float* w    = (const float*)d_in[4];
  const float* W1re = (const float*)d_in[5];
  const float* W1im = (const float*)d_in[6];
  const float* b1re = (const float*)d_in[7];
  const float* b1im = (const float*)d_in[8];
  const float* W2re = (const float*)d_in[9];
  const float* W2im = (const float*)d_in[10];
  const float* b2re = (const float*)d_in[11];
  const float* b2im = (const float*)d_in[12];
  const float* W3re = (const float*)d_in[13];
  const float* W3im = (const float*)d_in[14];
  const float* b3re = (const float*)d_in[15];
  const float* b3im = (const float*)d_in[16];
  const float* W4re = (const float*)d_in[17];
  const float* W4im = (const float*)d_in[18];
  const float* b4re = (const float*)d_in[19];

  const size_t NV = (size_t)NS * BS * UU * NT * DD;   // 229376
  float2* Vcur = (float2*)d_ws;
  float2* Z2b  = Vcur + NV;
  float2* Yb   = Z2b + NV;
  float2* IGb  = Yb + (size_t)NS * BS * UU * NR * DD;
  _Float16* Bpack = (_Float16*)(IGb + (size_t)NS * BS * UU * 4);

  k_pack<<<609, 256, 0, stream>>>(W1re, W1im, b1re, b1im, W2re, W2im, b2re, b2im,
                                  W3re, W3im, b3re, b3im, Bpack);
  k_norm0<<<NS * BS, 128, 0, stream>>>(Vre, Vim, Vcur);
  for (int it = 0; it < 3; ++it) {
    k_stage1<<<NS * BS * UU, 64, 0, stream>>>(Hre, Him, Vcur, Yb, IGb);
    k_stage2<<<NS * BS * UU, 64, 0, stream>>>(Hre, Him, Vcur, Yb, IGb, w, Z2b);
    float2* vout = (it == 2) ? (float2*)d_out : Vcur;
    k_mlp_mfma<<<NS * BS / 8, 256, 0, stream>>>(Vcur, Z2b,
        Bpack + (size_t)it * BITER_HALVES,
        W4re + it * HID, W4im + it * HID, b4re + it, vout);
  }
}

// Round 3
// 322.454 us; speedup vs baseline: 4.2231x; 1.3194x over previous
//
#include <hip/hip_runtime.h>
#include <math.h>

#define NS 256
#define BS 7
#define UU 8
#define NR 4
#define NT 8
#define DD 2
#define HID 200
#define CIN 32
#define PP 100.0f
#define NOISEF 1e-7f

typedef _Float16 f16x8 __attribute__((ext_vector_type(8)));
typedef float f32x4 __attribute__((ext_vector_type(4)));

#define AST 424      // big activation buffer row stride (halves)
#define AST0 104     // layer-1 input stride (halves)
#define NTILES 28
#define B1_KC 3
#define B23_KC 13
#define B1_HALVES (B1_KC*NTILES*64*8)
#define B23_HALVES (B23_KC*NTILES*64*8)
#define BITER_HALVES (B1_HALVES + 2*B23_HALVES)

// ---------------- 4x4 complex Hermitian PD solve, 2 RHS (Cholesky) ----------------
__device__ void chol_solve(const float2 (*A)[NR], const float2 (*B)[DD], float2 (*X)[DD]) {
  float2 L[NR][NR];
  for (int j = 0; j < NR; ++j) {
    float d = A[j][j].x;
    for (int k = 0; k < j; ++k) d -= L[j][k].x * L[j][k].x + L[j][k].y * L[j][k].y;
    float ld = sqrtf(fmaxf(d, 1e-30f));
    L[j][j] = make_float2(ld, 0.f);
    float inv = 1.f / ld;
    for (int i = j + 1; i < NR; ++i) {
      float sr = A[i][j].x, si = A[i][j].y;
      for (int k = 0; k < j; ++k) {
        float2 a = L[i][k], b = L[j][k];
        sr -= a.x * b.x + a.y * b.y;
        si -= a.y * b.x - a.x * b.y;
      }
      L[i][j] = make_float2(sr * inv, si * inv);
    }
  }
  for (int c = 0; c < DD; ++c) {
    float2 z[NR];
    for (int i = 0; i < NR; ++i) {
      float sr = B[i][c].x, si = B[i][c].y;
      for (int k = 0; k < i; ++k) {
        float2 a = L[i][k], zz = z[k];
        sr -= a.x * zz.x - a.y * zz.y;
        si -= a.x * zz.y + a.y * zz.x;
      }
      float inv = 1.f / L[i][i].x;
      z[i] = make_float2(sr * inv, si * inv);
    }
    for (int i = NR - 1; i >= 0; --i) {
      float sr = z[i].x, si = z[i].y;
      for (int k = i + 1; k < NR; ++k) {
        float2 a = L[k][i], xx = X[k][c];
        sr -= a.x * xx.x + a.y * xx.y;
        si -= a.x * xx.y - a.y * xx.x;
      }
      float inv = 1.f / L[i][i].x;
      X[i][c] = make_float2(sr * inv, si * inv);
    }
  }
}

// ---------------- K0: initial power normalization ----------------
__global__ void k_norm0(const float* __restrict__ Vre, const float* __restrict__ Vim,
                        float2* __restrict__ Vcur) {
  int nl = blockIdx.x;
  int tid = threadIdx.x;
  size_t base = (size_t)nl * 128;
  float re = Vre[base + tid], im = Vim[base + tid];
  float p = re * re + im * im;
  p += __shfl_down(p, 32); p += __shfl_down(p, 16); p += __shfl_down(p, 8);
  p += __shfl_down(p, 4);  p += __shfl_down(p, 2);  p += __shfl_down(p, 1);
  __shared__ float sred[2];
  if ((tid & 63) == 0) sred[tid >> 6] = p;
  __syncthreads();
  float fro = sred[0] + sred[1];
  float sc = sqrtf(PP / fro);
  Vcur[base + tid] = make_float2(re * sc, im * sc);
}

// ---------------- k_hv: block per (n,l): HV -> Usum, F, HV2 ----------------
__global__ __launch_bounds__(256) void k_hv(const float* __restrict__ Hre,
    const float* __restrict__ Him, const float2* __restrict__ Vcur,
    float2* __restrict__ Usb, float2* __restrict__ Fsb, float2* __restrict__ HV2b) {
  int nl = blockIdx.x; int l = nl % BS; int n = nl / BS;
  int tid = threadIdx.x;
  __shared__ float2 Hs[1792];    // [k][i][r][t]: k*256 + i*32 + r*8 + t
  __shared__ float2 Vs[952];     // [k][j]: (k*8+j)*17 + t*2 + d   (pad 17)
  __shared__ float2 HVs[3584];   // i*448 + k*64 + j*8 + r*2 + d
  __shared__ float2 Gp[256];     // half*128 + i*16 + r*4 + s

  for (int idx = tid; idx < 1792; idx += 256) {
    int k = idx >> 8, irt = idx & 255;
    size_t off = ((size_t)(n * BS + k) * BS + l) * 256 + irt;
    Hs[idx] = make_float2(Hre[off], Him[off]);
  }
  const float2* Vn = Vcur + (size_t)n * 896;
  for (int idx = tid; idx < 896; idx += 256) {
    int kj = idx >> 4, td = idx & 15;
    Vs[kj * 17 + td] = Vn[idx];
  }
  __syncthreads();

  // HV[i][k][j][r][d] = sum_t H[k,i,r,t] * V[k,j,t,d]
  for (int idx = tid; idx < 3584; idx += 256) {
    int d = idx & 1, r = (idx >> 1) & 3, j = (idx >> 3) & 7, i = (idx >> 6) & 7, k = idx >> 9;
    const float2* hp = &Hs[k * 256 + i * 32 + r * 8];
    const float2* vp = &Vs[(k * 8 + j) * 17 + d];
    float ar = 0.f, ai = 0.f;
    #pragma unroll
    for (int t = 0; t < NT; ++t) {
      float2 h = hp[t], v = vp[t * 2];
      ar += h.x * v.x - h.y * v.y;
      ai += h.x * v.y + h.y * v.x;
    }
    HVs[i * 448 + k * 64 + j * 8 + r * 2 + d] = make_float2(ar, ai);
  }
  __syncthreads();

  // Gram partials: Usum[i][r][s] = sum_{k,j,d} HV * conj(HV), k split in halves
  {
    int half = tid >> 7, i = (tid >> 4) & 7, r = (tid >> 2) & 3, s = tid & 3;
    int k0 = half ? 4 : 0, k1 = half ? 7 : 4;
    float ur = 0.f, ui = 0.f;
    for (int k = k0; k < k1; ++k) {
      const float2* base = &HVs[i * 448 + k * 64];
      #pragma unroll
      for (int j = 0; j < UU; ++j)
        #pragma unroll
        for (int d = 0; d < DD; ++d) {
          float2 a = base[j * 8 + r * 2 + d];
          float2 c = base[j * 8 + s * 2 + d];
          ur += a.x * c.x + a.y * c.y;
          ui += a.y * c.x - a.x * c.y;
        }
    }
    Gp[tid] = make_float2(ur, ui);
  }
  __syncthreads();

  if (tid < 128) {
    int i = tid >> 4, r = (tid >> 2) & 3, s = tid & 3;
    float2 g0 = Gp[tid], g1 = Gp[128 + tid];
    float ur = g0.x + g1.x, ui = g0.y + g1.y;
    if (r == s) ur += NOISEF;
    float tr = 0.f, ti = 0.f;
    #pragma unroll
    for (int d = 0; d < DD; ++d) {
      float2 a = HVs[i * 448 + l * 64 + i * 8 + r * 2 + d];
      float2 c = HVs[i * 448 + l * 64 + i * 8 + s * 2 + d];
      tr += a.x * c.x + a.y * c.y;
      ti += a.y * c.x - a.x * c.y;
    }
    size_t ob = (size_t)(nl * 8 + i) * 16 + r * 4 + s;
    Usb[ob] = make_float2(ur, ui);
    Fsb[ob] = make_float2(ur - tr, ui - ti);
  }
  if (tid < 64) {
    int i = tid >> 3, rd = tid & 7;
    HV2b[(size_t)(nl * 8 + i) * 8 + rd] = HVs[i * 448 + l * 64 + i * 8 + rd];
  }
}

// ---------------- k_solve: 1 thread per 4x4 solve (U->Y, F->IG) ----------------
__global__ __launch_bounds__(256) void k_solve(const float2* __restrict__ Usb,
    const float2* __restrict__ Fsb, const float2* __restrict__ HV2b,
    float2* __restrict__ Yb, float2* __restrict__ IGb) {
  int gid = blockIdx.x * 256 + threadIdx.x;      // 0..28671
  int which = (gid >= 14336) ? 1 : 0;
  int b = gid - which * 14336;
  float2 M[NR][NR], Bv[NR][DD], X[NR][DD];
  const float2* mp = (which ? Fsb : Usb) + (size_t)b * 16;
  #pragma unroll
  for (int x = 0; x < 16; ++x) M[x >> 2][x & 3] = mp[x];
  const float2* hp = HV2b + (size_t)b * 8;
  #pragma unroll
  for (int x = 0; x < 8; ++x) Bv[x >> 1][x & 1] = hp[x];
  chol_solve(M, Bv, X);
  if (!which) {
    #pragma unroll
    for (int r = 0; r < NR; ++r)
      #pragma unroll
      for (int d = 0; d < DD; ++d)
        Yb[(size_t)b * 8 + r * 2 + d] = X[r][d];
  } else {
    #pragma unroll
    for (int d = 0; d < DD; ++d)
      #pragma unroll
      for (int e = 0; e < DD; ++e) {
        float gr = (d == e) ? 1.f : 0.f, gi = 0.f;
        #pragma unroll
        for (int r = 0; r < NR; ++r) {
          float2 a = Bv[r][d], x = X[r][e];
          gr += a.x * x.x + a.y * x.y;
          gi += a.x * x.y - a.y * x.x;
        }
        IGb[(size_t)b * 4 + d * 2 + e] = make_float2(gr, gi);
      }
  }
}

// ---------------- k_stage2: block per (n,l): A, B=A*IG, L, Lam -> Z2 ----------------
__global__ __launch_bounds__(256) void k_stage2(const float* __restrict__ Hre,
    const float* __restrict__ Him, const float2* __restrict__ Vcur,
    const float2* __restrict__ Yb, const float2* __restrict__ IGb,
    const float* __restrict__ w, float2* __restrict__ Z2out) {
  int nl = blockIdx.x; int l = nl % BS; int n = nl / BS;
  int tid = threadIdx.x;
  __shared__ float2 SM[3686];
  float2* Hsm  = SM;            // [u][r][m][t]: ((u*4+r)*7+m)*8+t   (1792)
  float2* Bsm  = SM;            // after A: u*119 + m*17 + t*2 + e   (952)
  float2* Lsm  = SM + 952;      // (u*8+t)*8 + s                     (512)
  float2* Ysm  = SM + 1792;     // m*65 + u*8 + r*2 + d              (455)
  float2* IGsm = SM + 2247;     // m*33 + u*4 + d*2 + e              (231)
  float2* Asm  = SM + 2478;     // u*119 + m*17 + t*2 + d            (952)
  float2* Lamm = SM + 3430;     // u*16 + t*2 + e                    (128)
  float2* Zlm  = SM + 3558;     // u*16 + t*2 + d                    (128)

  size_t hbase = ((size_t)n * BS + l) * 1792;     // H[n,l,...] contiguous
  for (int idx = tid; idx < 1792; idx += 256) {
    int t = idx & 7, r = (idx >> 3) & 3, u = (idx >> 5) & 7, m = idx >> 8;
    Hsm[((u * 4 + r) * 7 + m) * 8 + t] = make_float2(Hre[hbase + idx], Him[hbase + idx]);
  }
  const float2* yp = Yb + (size_t)n * 448;
  for (int idx = tid; idx < 448; idx += 256)
    Ysm[(idx >> 6) * 65 + (idx & 63)] = yp[idx];
  const float2* igp = IGb + (size_t)n * 224;
  if (tid < 224) IGsm[(tid >> 5) * 33 + (tid & 31)] = igp[tid];
  const float2* zp = Vcur + (size_t)nl * 128;
  if (tid < 128) Zlm[tid] = zp[tid];
  __syncthreads();

  // A[u][m][t][d] = sum_r conj(H) * Y
  for (int idx = tid; idx < 896; idx += 256) {
    int u = idx / 112, rem = idx % 112, m = rem >> 4, t = (rem >> 1) & 7, d = rem & 1;
    float ar = 0.f, ai = 0.f;
    #pragma unroll
    for (int r = 0; r < NR; ++r) {
      float2 h = Hsm[((u * 4 + r) * 7 + m) * 8 + t];
      float2 y = Ysm[m * 65 + u * 8 + r * 2 + d];
      ar += h.x * y.x + h.y * y.y;
      ai += h.x * y.y - h.y * y.x;
    }
    Asm[u * 119 + m * 17 + t * 2 + d] = make_float2(ar, ai);
  }
  __syncthreads();

  // B[u][m][t][e] = sum_d A * IG[m]    (overlays Hs region)
  for (int idx = tid; idx < 896; idx += 256) {
    int u = idx / 112, rem = idx % 112, m = rem >> 4, t = (rem >> 1) & 7, e = rem & 1;
    float br = 0.f, bi = 0.f;
    #pragma unroll
    for (int d = 0; d < DD; ++d) {
      float2 a = Asm[u * 119 + m * 17 + t * 2 + d];
      float2 g = IGsm[m * 33 + u * 4 + d * 2 + e];
      br += a.x * g.x - a.y * g.y;
      bi += a.x * g.y + a.y * g.x;
    }
    Bsm[u * 119 + m * 17 + t * 2 + e] = make_float2(br, bi);
  }
  __syncthreads();

  // L[u][t][s] = w_u * sum_{m,e} B * conj(A[s])
  for (int idx = tid; idx < 512; idx += 256) {
    int u = idx >> 6, t = (idx >> 3) & 7, s = idx & 7;
    float lr = 0.f, li = 0.f;
    #pragma unroll
    for (int m = 0; m < BS; ++m)
      #pragma unroll
      for (int e = 0; e < DD; ++e) {
        float2 bb = Bsm[u * 119 + m * 17 + t * 2 + e];
        float2 ac = Asm[u * 119 + m * 17 + s * 2 + e];
        lr += bb.x * ac.x + bb.y * ac.y;
        li += bb.y * ac.x - bb.x * ac.y;
      }
    float wu = w[u];
    Lsm[(u * 8 + t) * 8 + s] = make_float2(lr * wu, li * wu);
  }
  // Lam[u][t][e] = w_u * sum_d A[u][l][t][d] * IG[l][u][d][e]
  if (tid < 128) {
    int u = tid >> 4, t = (tid >> 1) & 7, e = tid & 1;
    float ar = 0.f, ai = 0.f;
    #pragma unroll
    for (int d = 0; d < DD; ++d) {
      float2 a = Asm[u * 119 + l * 17 + t * 2 + d];
      float2 g = IGsm[l * 33 + u * 4 + d * 2 + e];
      ar += a.x * g.x - a.y * g.y;
      ai += a.x * g.y + a.y * g.x;
    }
    float wu = w[u];
    Lamm[u * 16 + t * 2 + e] = make_float2(ar * wu, ai * wu);
  }
  __syncthreads();

  // Z2 = Lam - L . Z
  if (tid < 128) {
    int u = tid >> 4, t = (tid >> 1) & 7, d = tid & 1;
    float2 lam = Lamm[u * 16 + t * 2 + d];
    float zr = lam.x, zi = lam.y;
    #pragma unroll
    for (int s = 0; s < NT; ++s) {
      float2 Lts = Lsm[(u * 8 + t) * 8 + s];
      float2 z = Zlm[u * 16 + s * 2 + d];
      zr -= Lts.x * z.x - Lts.y * z.y;
      zi -= Lts.x * z.y + Lts.y * z.x;
    }
    Z2out[(size_t)nl * 128 + u * 16 + t * 2 + d] = make_float2(zr, zi);
  }
}

// ---------------- Bpack: weights -> fragment-major fp16 real-GEMM form ----------------
__global__ __launch_bounds__(256) void k_pack(
    const float* __restrict__ W1re, const float* __restrict__ W1im,
    const float* __restrict__ b1re, const float* __restrict__ b1im,
    const float* __restrict__ W2re, const float* __restrict__ W2im,
    const float* __restrict__ b2re, const float* __restrict__ b2im,
    const float* __restrict__ W3re, const float* __restrict__ W3im,
    const float* __restrict__ b3re, const float* __restrict__ b3im,
    _Float16* __restrict__ Bout) {
  int gid = blockIdx.x * 256 + threadIdx.x;
  int lane = gid & 63;
  int rest = gid >> 6;
  int nt = rest % NTILES;
  int id2 = rest / NTILES;
  if (id2 >= 87) return;
  int iter = id2 / 29, kk = id2 % 29;
  int layer, kc;
  if (kk < 3)       { layer = 0; kc = kk; }
  else if (kk < 16) { layer = 1; kc = kk - 3; }
  else              { layer = 2; kc = kk - 16; }
  const float *Wr, *Wi, *br, *bi;
  if (layer == 0) { Wr = W1re + iter*HID*CIN; Wi = W1im + iter*HID*CIN; br = b1re + iter*HID; bi = b1im + iter*HID; }
  else if (layer == 1) { Wr = W2re + iter*HID*HID; Wi = W2im + iter*HID*HID; br = b2re + iter*HID; bi = b2im + iter*HID; }
  else { Wr = W3re + iter*HID*HID; Wi = W3im + iter*HID*HID; br = b3re + iter*HID; bi = b3im + iter*HID; }
  int c = nt * 16 + (lane & 15);
  int o = c >> 1; int odd = c & 1;
  f16x8 frag;
  #pragma unroll
  for (int j = 0; j < 8; ++j) {
    int k = kc * 32 + (lane >> 4) * 8 + j;
    float v = 0.f;
    if (o < HID) {
      if (layer == 0) {
        if (k < 32)       v = odd ? Wi[o*32 + k] : Wr[o*32 + k];
        else if (k < 64)  { int i = k - 32; v = odd ? Wr[o*32 + i] : -Wi[o*32 + i]; }
        else if (k == 64) v = odd ? bi[o] : br[o];
      } else {
        if (k < 200)       v = odd ? Wi[o*200 + k] : Wr[o*200 + k];
        else if (k == 207) v = odd ? bi[o] : br[o];
        else if (k >= 208 && k < 408) { int i = k - 208; v = odd ? Wr[o*200 + i] : -Wi[o*200 + i]; }
      }
    }
    frag[j] = (_Float16)v;
  }
  size_t off = (size_t)iter * BITER_HALVES
             + (layer == 0 ? 0 : (layer == 1 ? B1_HALVES : (B1_HALVES + B23_HALVES)))
             + ((size_t)(kc * NTILES + nt) * 64 + lane) * 8;
  *(f16x8*)(Bout + off) = frag;
}

// ---------------- fused MFMA MLP ----------------
template<int ASTRIDE>
__device__ inline void do_gemm(const _Float16* Ain, int KC,
                               const _Float16* __restrict__ Bg,
                               _Float16* Aout, int wave, int lane) {
  f32x4 acc[4][7];
  #pragma unroll
  for (int rt = 0; rt < 4; ++rt)
    #pragma unroll
    for (int nt = 0; nt < 7; ++nt)
      acc[rt][nt] = (f32x4){0.f, 0.f, 0.f, 0.f};
  const int r0 = lane & 15, g = lane >> 4;
  #pragma unroll 2
  for (int kc = 0; kc < KC; ++kc) {
    f16x8 a0 = *(const f16x8*)(Ain + (r0 +  0) * ASTRIDE + kc * 32 + 8 * g);
    f16x8 a1 = *(const f16x8*)(Ain + (r0 + 16) * ASTRIDE + kc * 32 + 8 * g);
    f16x8 a2 = *(const f16x8*)(Ain + (r0 + 32) * ASTRIDE + kc * 32 + 8 * g);
    f16x8 a3 = *(const f16x8*)(Ain + (r0 + 48) * ASTRIDE + kc * 32 + 8 * g);
    const _Float16* bp = Bg + ((size_t)(kc * NTILES + wave * 7) * 64 + lane) * 8;
    #pragma unroll
    for (int nt = 0; nt < 7; ++nt) {
      f16x8 b = *(const f16x8*)(bp + nt * 64 * 8);
      acc[0][nt] = __builtin_amdgcn_mfma_f32_16x16x32_f16(a0, b, acc[0][nt], 0, 0, 0);
      acc[1][nt] = __builtin_amdgcn_mfma_f32_16x16x32_f16(a1, b, acc[1][nt], 0, 0, 0);
      acc[2][nt] = __builtin_amdgcn_mfma_f32_16x16x32_f16(a2, b, acc[2][nt], 0, 0, 0);
      acc[3][nt] = __builtin_amdgcn_mfma_f32_16x16x32_f16(a3, b, acc[3][nt], 0, 0, 0);
    }
  }
  int cbase = wave * 7 * 16 + r0;
  #pragma unroll
  for (int nt = 0; nt < 7; ++nt) {
    int c = cbase + nt * 16;
    int o = c >> 1;
    bool isre = !(c & 1);
    if (o < HID) {
      _Float16* outp = Aout + (isre ? o : 208 + o);
      #pragma unroll
      for (int rt = 0; rt < 4; ++rt)
        #pragma unroll
        for (int q = 0; q < 4; ++q) {
          float v = acc[rt][nt][q];
          if (isre) v = fmaxf(v, 0.f);
          outp[(size_t)(rt * 16 + g * 4 + q) * AST] = (_Float16)v;
        }
    }
  }
}

__global__ __launch_bounds__(256, 1) void k_mlp_mfma(
    const float2* __restrict__ Vcur, const float2* __restrict__ Z2,
    const _Float16* __restrict__ Bp,
    const float* __restrict__ W4re, const float* __restrict__ W4im,
    const float* __restrict__ b4re,
    float2* __restrict__ Vout) {
  int b = blockIdx.x;
  int tid = threadIdx.x;
  int wave = tid >> 6, lane = tid & 63;

  __shared__ _Float16 A0[64 * AST0];
  __shared__ _Float16 Abuf[2][64 * AST];
  __shared__ float2 Zs[64][16];
  __shared__ float2 Z2s[64][16];
  __shared__ float w4s[2][HID];
  __shared__ float stepv[64];
  __shared__ float scs[8];

  for (int idx = tid; idx < 1024; idx += 256) {
    ((float2*)Zs)[idx]  = Vcur[(size_t)b * 1024 + idx];
    ((float2*)Z2s)[idx] = Z2[(size_t)b * 1024 + idx];
  }
  for (int idx = tid; idx < HID; idx += 256) {
    w4s[0][idx] = W4re[idx];
    w4s[1][idx] = W4im[idx];
  }
  __syncthreads();

  for (int idx = tid; idx < 64 * AST0; idx += 256) {
    int m = idx / AST0, c = idx % AST0;
    float v;
    if (c < 64) {
      int f = c & 31;
      float2 z = (f < 16) ? Zs[m][f] : Z2s[m][f - 16];
      v = (c >= 32) ? z.y : z.x;
    } else v = (c == 64) ? 1.f : 0.f;
    A0[m * AST0 + c] = (_Float16)v;
  }
  for (int idx = tid; idx < 2 * 64 * 16; idx += 256) {
    int buf = idx >> 10, rem = idx & 1023, m = rem >> 4, p = rem & 15;
    int c = (p < 8) ? (200 + p) : (400 + p);
    Abuf[buf][m * AST + c] = (p == 7) ? (_Float16)1.f : (_Float16)0.f;
  }
  __syncthreads();

  do_gemm<AST0>(A0, B1_KC, Bp, &Abuf[0][0], wave, lane);
  __syncthreads();
  do_gemm<AST>(&Abuf[0][0], B23_KC, Bp + B1_HALVES, &Abuf[1][0], wave, lane);
  __syncthreads();
  do_gemm<AST>(&Abuf[1][0], B23_KC, Bp + B1_HALVES + B23_HALVES, &Abuf[0][0], wave, lane);
  __syncthreads();

  {
    int m = tid >> 2, q = tid & 3;
    float acc = 0.f;
    for (int o = q; o < HID; o += 4) {
      float hr = (float)Abuf[0][m * AST + o];
      float hi = (float)Abuf[0][m * AST + 208 + o];
      acc += hr * w4s[0][o] - hi * w4s[1][o];
    }
    acc += __shfl_down(acc, 2);
    acc += __shfl_down(acc, 1);
    if (q == 0) stepv[m] = acc + b4re[0];
  }
  __syncthreads();

  for (int idx = tid; idx < 1024; idx += 256) {
    int m = idx >> 4, f = idx & 15;
    float st = stepv[m];
    float2 z = Zs[m][f], z2 = Z2s[m][f];
    Zs[m][f] = make_float2(fmaf(st, z2.x, z.x), fmaf(st, z2.y, z.y));
  }
  __syncthreads();

  for (int h = 0; h < 2; ++h) {
    int nl = wave * 2 + h;
    const float2* vp = &Zs[nl * 8][0];
    float2 v0 = vp[lane * 2], v1 = vp[lane * 2 + 1];
    float p = v0.x * v0.x + v0.y * v0.y + v1.x * v1.x + v1.y * v1.y;
    p += __shfl_down(p, 32); p += __shfl_down(p, 16); p += __shfl_down(p, 8);
    p += __shfl_down(p, 4);  p += __shfl_down(p, 2);  p += __shfl_down(p, 1);
    if (lane == 0) scs[nl] = (p > PP) ? sqrtf(PP / p) : 1.f;
  }
  __syncthreads();
  for (int idx = tid; idx < 1024; idx += 256) {
    float sc = scs[idx >> 7];
    float2 v = ((float2*)Zs)[idx];
    Vout[(size_t)b * 1024 + idx] = make_float2(v.x * sc, v.y * sc);
  }
}

// ---------------- launch ----------------
extern "C" void kernel_launch(void* const* d_in, const int* in_sizes, int n_in,
                              void* d_out, int out_size, void* d_ws, size_t ws_size,
                              hipStream_t stream) {
  const float* Hre  = (const float*)d_in[0];
  const float* Him  = (const float*)d_in[1];
  const float* Vre  = (const float*)d_in[2];
  const float* Vim  = (const float*)d_in[3];
  const float* w    = (const float*)d_in[4];
  const float* W1re = (const float*)d_in[5];
  const float* W1im = (const float*)d_in[6];
  const float* b1re = (const float*)d_in[7];
  const float* b1im = (const float*)d_in[8];
  const float* W2re = (const float*)d_in[9];
  const float* W2im = (const float*)d_in[10];
  const float* b2re = (const float*)d_in[11];
  const float* b2im = (const float*)d_in[12];
  const float* W3re = (const float*)d_in[13];
  const float* W3im = (const float*)d_in[14];
  const float* b3re = (const float*)d_in[15];
  const float* b3im = (const float*)d_in[16];
  const float* W4re = (const float*)d_in[17];
  const float* W4im = (const float*)d_in[18];
  const float* b4re = (const float*)d_in[19];

  const size_t NV = (size_t)NS * BS * UU * NT * DD;   // 229376
  const size_t NB = (size_t)NS * BS * UU;             // 14336
  float2* Vcur = (float2*)d_ws;
  float2* Z2b  = Vcur + NV;
  float2* Yb   = Z2b + NV;
  float2* IGb  = Yb + NB * 8;
  float2* Usb  = IGb + NB * 4;
  float2* Fsb  = Usb + NB * 16;
  float2* HV2b = Fsb + NB * 16;
  _Float16* Bpack = (_Float16*)(HV2b + NB * 8);

  k_pack<<<609, 256, 0, stream>>>(W1re, W1im, b1re, b1im, W2re, W2im, b2re, b2im,
                                  W3re, W3im, b3re, b3im, Bpack);
  k_norm0<<<NS * BS, 128, 0, stream>>>(Vre, Vim, Vcur);
  for (int it = 0; it < 3; ++it) {
    k_hv<<<NS * BS, 256, 0, stream>>>(Hre, Him, Vcur, Usb, Fsb, HV2b);
    k_solve<<<112, 256, 0, stream>>>(Usb, Fsb, HV2b, Yb, IGb);
    k_stage2<<<NS * BS, 256, 0, stream>>>(Hre, Him, Vcur, Yb, IGb, w, Z2b);
    float2* vout = (it == 2) ? (float2*)d_out : Vcur;
    k_mlp_mfma<<<NS * BS / 8, 256, 0, stream>>>(Vcur, Z2b,
        Bpack + (size_t)it * BITER_HALVES,
        W4re + it * HID, W4im + it * HID, b4re + it, vout);
  }
}

// Round 4
// 269.938 us; speedup vs baseline: 5.0447x; 1.1945x over previous
//
#include <hip/hip_runtime.h>
#include <math.h>

#define NS 256
#define BS 7
#define UU 8
#define NR 4
#define NT 8
#define DD 2
#define HID 200
#define CIN 32
#define PP 100.0f
#define NOISEF 1e-7f

typedef _Float16 f16x8 __attribute__((ext_vector_type(8)));
typedef float f32x4 __attribute__((ext_vector_type(4)));

#define AST 424      // big activation buffer row stride (halves)
#define AST0 104     // layer-1 input stride (halves)
#define NTILES 28
#define B1_KC 3
#define B23_KC 13
#define B1_HALVES (B1_KC*NTILES*64*8)
#define B23_HALVES (B23_KC*NTILES*64*8)
#define BITER_HALVES (B1_HALVES + 2*B23_HALVES)

// ---------------- 4x4 complex Hermitian PD solve, 2 RHS (Cholesky) ----------------
__device__ void chol_solve(const float2 (*A)[NR], const float2 (*B)[DD], float2 (*X)[DD]) {
  float2 L[NR][NR];
  for (int j = 0; j < NR; ++j) {
    float d = A[j][j].x;
    for (int k = 0; k < j; ++k) d -= L[j][k].x * L[j][k].x + L[j][k].y * L[j][k].y;
    float ld = sqrtf(fmaxf(d, 1e-30f));
    L[j][j] = make_float2(ld, 0.f);
    float inv = 1.f / ld;
    for (int i = j + 1; i < NR; ++i) {
      float sr = A[i][j].x, si = A[i][j].y;
      for (int k = 0; k < j; ++k) {
        float2 a = L[i][k], b = L[j][k];
        sr -= a.x * b.x + a.y * b.y;
        si -= a.y * b.x - a.x * b.y;
      }
      L[i][j] = make_float2(sr * inv, si * inv);
    }
  }
  for (int c = 0; c < DD; ++c) {
    float2 z[NR];
    for (int i = 0; i < NR; ++i) {
      float sr = B[i][c].x, si = B[i][c].y;
      for (int k = 0; k < i; ++k) {
        float2 a = L[i][k], zz = z[k];
        sr -= a.x * zz.x - a.y * zz.y;
        si -= a.x * zz.y + a.y * zz.x;
      }
      float inv = 1.f / L[i][i].x;
      z[i] = make_float2(sr * inv, si * inv);
    }
    for (int i = NR - 1; i >= 0; --i) {
      float sr = z[i].x, si = z[i].y;
      for (int k = i + 1; k < NR; ++k) {
        float2 a = L[k][i], xx = X[k][c];
        sr -= a.x * xx.x + a.y * xx.y;
        si -= a.x * xx.y - a.y * xx.x;
      }
      float inv = 1.f / L[i][i].x;
      X[i][c] = make_float2(sr * inv, si * inv);
    }
  }
}

// ---------------- K0: initial power normalization ----------------
__global__ void k_norm0(const float* __restrict__ Vre, const float* __restrict__ Vim,
                        float2* __restrict__ Vcur) {
  int nl = blockIdx.x;
  int tid = threadIdx.x;
  size_t base = (size_t)nl * 128;
  float re = Vre[base + tid], im = Vim[base + tid];
  float p = re * re + im * im;
  p += __shfl_down(p, 32); p += __shfl_down(p, 16); p += __shfl_down(p, 8);
  p += __shfl_down(p, 4);  p += __shfl_down(p, 2);  p += __shfl_down(p, 1);
  __shared__ float sred[2];
  if ((tid & 63) == 0) sred[tid >> 6] = p;
  __syncthreads();
  float fro = sred[0] + sred[1];
  float sc = sqrtf(PP / fro);
  Vcur[base + tid] = make_float2(re * sc, im * sc);
}

// ---------------- k_hv: block per (n,l): HV -> Usum/F/HV2 -> solves -> Y, IG ----------------
__global__ __launch_bounds__(256) void k_hv(const float* __restrict__ Hre,
    const float* __restrict__ Him, const float2* __restrict__ Vcur,
    float2* __restrict__ Yb, float2* __restrict__ IGb) {
  int nl = blockIdx.x; int l = nl % BS; int n = nl / BS;
  int tid = threadIdx.x;
  __shared__ float2 Hs[1792];    // [k][i][r][t]: k*256 + i*32 + r*8 + t
  __shared__ float2 Vs[952];     // [k][j]: (k*8+j)*17 + t*2 + d
  __shared__ float2 HVs[3584];   // i*448 + k*64 + j*8 + r*2 + d
  __shared__ float2 Gp[256];
  __shared__ float2 UsL[128];    // i*16 + r*4 + s
  __shared__ float2 FsL[128];
  __shared__ float2 HV2L[64];    // i*8 + r*2 + d

  for (int idx = tid; idx < 1792; idx += 256) {
    int k = idx >> 8, irt = idx & 255;
    size_t off = ((size_t)(n * BS + k) * BS + l) * 256 + irt;
    Hs[idx] = make_float2(Hre[off], Him[off]);
  }
  const float2* Vn = Vcur + (size_t)n * 896;
  for (int idx = tid; idx < 896; idx += 256) {
    int kj = idx >> 4, td = idx & 15;
    Vs[kj * 17 + td] = Vn[idx];
  }
  __syncthreads();

  for (int idx = tid; idx < 3584; idx += 256) {
    int d = idx & 1, r = (idx >> 1) & 3, j = (idx >> 3) & 7, i = (idx >> 6) & 7, k = idx >> 9;
    const float2* hp = &Hs[k * 256 + i * 32 + r * 8];
    const float2* vp = &Vs[(k * 8 + j) * 17 + d];
    float ar = 0.f, ai = 0.f;
    #pragma unroll
    for (int t = 0; t < NT; ++t) {
      float2 h = hp[t], v = vp[t * 2];
      ar += h.x * v.x - h.y * v.y;
      ai += h.x * v.y + h.y * v.x;
    }
    HVs[i * 448 + k * 64 + j * 8 + r * 2 + d] = make_float2(ar, ai);
  }
  __syncthreads();

  {
    int half = tid >> 7, i = (tid >> 4) & 7, r = (tid >> 2) & 3, s = tid & 3;
    int k0 = half ? 4 : 0, k1 = half ? 7 : 4;
    float ur = 0.f, ui = 0.f;
    for (int k = k0; k < k1; ++k) {
      const float2* base = &HVs[i * 448 + k * 64];
      #pragma unroll
      for (int j = 0; j < UU; ++j)
        #pragma unroll
        for (int d = 0; d < DD; ++d) {
          float2 a = base[j * 8 + r * 2 + d];
          float2 c = base[j * 8 + s * 2 + d];
          ur += a.x * c.x + a.y * c.y;
          ui += a.y * c.x - a.x * c.y;
        }
    }
    Gp[tid] = make_float2(ur, ui);
  }
  __syncthreads();

  if (tid < 128) {
    int i = tid >> 4, r = (tid >> 2) & 3, s = tid & 3;
    float2 g0 = Gp[tid], g1 = Gp[128 + tid];
    float ur = g0.x + g1.x, ui = g0.y + g1.y;
    if (r == s) ur += NOISEF;
    float tr = 0.f, ti = 0.f;
    #pragma unroll
    for (int d = 0; d < DD; ++d) {
      float2 a = HVs[i * 448 + l * 64 + i * 8 + r * 2 + d];
      float2 c = HVs[i * 448 + l * 64 + i * 8 + s * 2 + d];
      tr += a.x * c.x + a.y * c.y;
      ti += a.y * c.x - a.x * c.y;
    }
    UsL[tid] = make_float2(ur, ui);
    FsL[tid] = make_float2(ur - tr, ui - ti);
  }
  if (tid < 64) HV2L[tid] = HVs[(tid >> 3) * 448 + l * 64 + (tid >> 3) * 8 + (tid & 7)];
  __syncthreads();

  // 16 solves: threads 0-7 -> U solve -> Y; threads 8-15 -> F solve -> IG
  if (tid < 16) {
    int i = tid & 7, which = tid >> 3;
    float2 M[NR][NR], Bv[NR][DD], X[NR][DD];
    const float2* mp = (which ? FsL : UsL) + i * 16;
    #pragma unroll
    for (int x = 0; x < 16; ++x) M[x >> 2][x & 3] = mp[x];
    #pragma unroll
    for (int x = 0; x < 8; ++x) Bv[x >> 1][x & 1] = HV2L[i * 8 + x];
    chol_solve(M, Bv, X);
    size_t b = (size_t)nl * 8 + i;
    if (!which) {
      #pragma unroll
      for (int x = 0; x < 8; ++x) Yb[b * 8 + x] = X[x >> 1][x & 1];
    } else {
      #pragma unroll
      for (int d = 0; d < DD; ++d)
        #pragma unroll
        for (int e = 0; e < DD; ++e) {
          float gr = (d == e) ? 1.f : 0.f, gi = 0.f;
          #pragma unroll
          for (int r = 0; r < NR; ++r) {
            float2 a = Bv[r][d], x = X[r][e];
            gr += a.x * x.x + a.y * x.y;
            gi += a.x * x.y - a.y * x.x;
          }
          IGb[b * 4 + d * 2 + e] = make_float2(gr, gi);
        }
    }
  }
}

// ---------------- k_stage2: block per (n,l): A, B=A*IG, L, Lam -> Z2 ----------------
__global__ __launch_bounds__(256) void k_stage2(const float* __restrict__ Hre,
    const float* __restrict__ Him, const float2* __restrict__ Vcur,
    const float2* __restrict__ Yb, const float2* __restrict__ IGb,
    const float* __restrict__ w, float2* __restrict__ Z2out) {
  int nl = blockIdx.x; int l = nl % BS; int n = nl / BS;
  int tid = threadIdx.x;
  __shared__ float2 SM[3686];
  float2* Hsm  = SM;
  float2* Bsm  = SM;
  float2* Lsm  = SM + 952;
  float2* Ysm  = SM + 1792;
  float2* IGsm = SM + 2247;
  float2* Asm  = SM + 2478;
  float2* Lamm = SM + 3430;
  float2* Zlm  = SM + 3558;

  size_t hbase = ((size_t)n * BS + l) * 1792;
  for (int idx = tid; idx < 1792; idx += 256) {
    int t = idx & 7, r = (idx >> 3) & 3, u = (idx >> 5) & 7, m = idx >> 8;
    Hsm[((u * 4 + r) * 7 + m) * 8 + t] = make_float2(Hre[hbase + idx], Him[hbase + idx]);
  }
  const float2* yp = Yb + (size_t)n * 448;
  for (int idx = tid; idx < 448; idx += 256)
    Ysm[(idx >> 6) * 65 + (idx & 63)] = yp[idx];
  const float2* igp = IGb + (size_t)n * 224;
  if (tid < 224) IGsm[(tid >> 5) * 33 + (tid & 31)] = igp[tid];
  const float2* zp = Vcur + (size_t)nl * 128;
  if (tid < 128) Zlm[tid] = zp[tid];
  __syncthreads();

  for (int idx = tid; idx < 896; idx += 256) {
    int u = idx / 112, rem = idx % 112, m = rem >> 4, t = (rem >> 1) & 7, d = rem & 1;
    float ar = 0.f, ai = 0.f;
    #pragma unroll
    for (int r = 0; r < NR; ++r) {
      float2 h = Hsm[((u * 4 + r) * 7 + m) * 8 + t];
      float2 y = Ysm[m * 65 + u * 8 + r * 2 + d];
      ar += h.x * y.x + h.y * y.y;
      ai += h.x * y.y - h.y * y.x;
    }
    Asm[u * 119 + m * 17 + t * 2 + d] = make_float2(ar, ai);
  }
  __syncthreads();

  for (int idx = tid; idx < 896; idx += 256) {
    int u = idx / 112, rem = idx % 112, m = rem >> 4, t = (rem >> 1) & 7, e = rem & 1;
    float br = 0.f, bi = 0.f;
    #pragma unroll
    for (int d = 0; d < DD; ++d) {
      float2 a = Asm[u * 119 + m * 17 + t * 2 + d];
      float2 g = IGsm[m * 33 + u * 4 + d * 2 + e];
      br += a.x * g.x - a.y * g.y;
      bi += a.x * g.y + a.y * g.x;
    }
    Bsm[u * 119 + m * 17 + t * 2 + e] = make_float2(br, bi);
  }
  __syncthreads();

  for (int idx = tid; idx < 512; idx += 256) {
    int u = idx >> 6, t = (idx >> 3) & 7, s = idx & 7;
    float lr = 0.f, li = 0.f;
    #pragma unroll
    for (int m = 0; m < BS; ++m)
      #pragma unroll
      for (int e = 0; e < DD; ++e) {
        float2 bb = Bsm[u * 119 + m * 17 + t * 2 + e];
        float2 ac = Asm[u * 119 + m * 17 + s * 2 + e];
        lr += bb.x * ac.x + bb.y * ac.y;
        li += bb.y * ac.x - bb.x * ac.y;
      }
    float wu = w[u];
    Lsm[(u * 8 + t) * 8 + s] = make_float2(lr * wu, li * wu);
  }
  if (tid < 128) {
    int u = tid >> 4, t = (tid >> 1) & 7, e = tid & 1;
    float ar = 0.f, ai = 0.f;
    #pragma unroll
    for (int d = 0; d < DD; ++d) {
      float2 a = Asm[u * 119 + l * 17 + t * 2 + d];
      float2 g = IGsm[l * 33 + u * 4 + d * 2 + e];
      ar += a.x * g.x - a.y * g.y;
      ai += a.x * g.y + a.y * g.x;
    }
    float wu = w[u];
    Lamm[u * 16 + t * 2 + e] = make_float2(ar * wu, ai * wu);
  }
  __syncthreads();

  if (tid < 128) {
    int u = tid >> 4, t = (tid >> 1) & 7, d = tid & 1;
    float2 lam = Lamm[u * 16 + t * 2 + d];
    float zr = lam.x, zi = lam.y;
    #pragma unroll
    for (int s = 0; s < NT; ++s) {
      float2 Lts = Lsm[(u * 8 + t) * 8 + s];
      float2 z = Zlm[u * 16 + s * 2 + d];
      zr -= Lts.x * z.x - Lts.y * z.y;
      zi -= Lts.x * z.y + Lts.y * z.x;
    }
    Z2out[(size_t)nl * 128 + u * 16 + t * 2 + d] = make_float2(zr, zi);
  }
}

// ---------------- Bpack ----------------
__global__ __launch_bounds__(256) void k_pack(
    const float* __restrict__ W1re, const float* __restrict__ W1im,
    const float* __restrict__ b1re, const float* __restrict__ b1im,
    const float* __restrict__ W2re, const float* __restrict__ W2im,
    const float* __restrict__ b2re, const float* __restrict__ b2im,
    const float* __restrict__ W3re, const float* __restrict__ W3im,
    const float* __restrict__ b3re, const float* __restrict__ b3im,
    _Float16* __restrict__ Bout) {
  int gid = blockIdx.x * 256 + threadIdx.x;
  int lane = gid & 63;
  int rest = gid >> 6;
  int nt = rest % NTILES;
  int id2 = rest / NTILES;
  if (id2 >= 87) return;
  int iter = id2 / 29, kk = id2 % 29;
  int layer, kc;
  if (kk < 3)       { layer = 0; kc = kk; }
  else if (kk < 16) { layer = 1; kc = kk - 3; }
  else              { layer = 2; kc = kk - 16; }
  const float *Wr, *Wi, *br, *bi;
  if (layer == 0) { Wr = W1re + iter*HID*CIN; Wi = W1im + iter*HID*CIN; br = b1re + iter*HID; bi = b1im + iter*HID; }
  else if (layer == 1) { Wr = W2re + iter*HID*HID; Wi = W2im + iter*HID*HID; br = b2re + iter*HID; bi = b2im + iter*HID; }
  else { Wr = W3re + iter*HID*HID; Wi = W3im + iter*HID*HID; br = b3re + iter*HID; bi = b3im + iter*HID; }
  int c = nt * 16 + (lane & 15);
  int o = c >> 1; int odd = c & 1;
  f16x8 frag;
  #pragma unroll
  for (int j = 0; j < 8; ++j) {
    int k = kc * 32 + (lane >> 4) * 8 + j;
    float v = 0.f;
    if (o < HID) {
      if (layer == 0) {
        if (k < 32)       v = odd ? Wi[o*32 + k] : Wr[o*32 + k];
        else if (k < 64)  { int i = k - 32; v = odd ? Wr[o*32 + i] : -Wi[o*32 + i]; }
        else if (k == 64) v = odd ? bi[o] : br[o];
      } else {
        if (k < 200)       v = odd ? Wi[o*200 + k] : Wr[o*200 + k];
        else if (k == 207) v = odd ? bi[o] : br[o];
        else if (k >= 208 && k < 408) { int i = k - 208; v = odd ? Wr[o*200 + i] : -Wi[o*200 + i]; }
      }
    }
    frag[j] = (_Float16)v;
  }
  size_t off = (size_t)iter * BITER_HALVES
             + (layer == 0 ? 0 : (layer == 1 ? B1_HALVES : (B1_HALVES + B23_HALVES)))
             + ((size_t)(kc * NTILES + nt) * 64 + lane) * 8;
  *(f16x8*)(Bout + off) = frag;
}

// ---------------- fused MFMA MLP (8 waves: 2 row x 4 col) ----------------
template<int ASTRIDE, int KC>
__device__ inline void do_gemm(const _Float16* Ain,
                               const _Float16* __restrict__ Bg,
                               _Float16* Aout, int wr, int wc, int lane) {
  f32x4 acc[2][7];
  #pragma unroll
  for (int rt = 0; rt < 2; ++rt)
    #pragma unroll
    for (int nt = 0; nt < 7; ++nt)
      acc[rt][nt] = (f32x4){0.f, 0.f, 0.f, 0.f};
  const int r0 = (lane & 15) + wr * 32, g = lane >> 4;
  const _Float16* bp0 = Bg + ((size_t)(wc * 7) * 64 + lane) * 8;
  f16x8 b[7];
  #pragma unroll
  for (int nt = 0; nt < 7; ++nt) b[nt] = *(const f16x8*)(bp0 + nt * 512);
  f16x8 a0 = *(const f16x8*)(Ain + r0 * ASTRIDE + 8 * g);
  f16x8 a1 = *(const f16x8*)(Ain + (r0 + 16) * ASTRIDE + 8 * g);
  #pragma unroll
  for (int kc = 0; kc < KC; ++kc) {
    f16x8 a0n, a1n, bn[7];
    if (kc + 1 < KC) {
      const _Float16* bpn = bp0 + (size_t)(kc + 1) * (NTILES * 512);
      #pragma unroll
      for (int nt = 0; nt < 7; ++nt) bn[nt] = *(const f16x8*)(bpn + nt * 512);
      a0n = *(const f16x8*)(Ain + r0 * ASTRIDE + (kc + 1) * 32 + 8 * g);
      a1n = *(const f16x8*)(Ain + (r0 + 16) * ASTRIDE + (kc + 1) * 32 + 8 * g);
    }
    #pragma unroll
    for (int nt = 0; nt < 7; ++nt) {
      acc[0][nt] = __builtin_amdgcn_mfma_f32_16x16x32_f16(a0, b[nt], acc[0][nt], 0, 0, 0);
      acc[1][nt] = __builtin_amdgcn_mfma_f32_16x16x32_f16(a1, b[nt], acc[1][nt], 0, 0, 0);
    }
    if (kc + 1 < KC) {
      a0 = a0n; a1 = a1n;
      #pragma unroll
      for (int nt = 0; nt < 7; ++nt) b[nt] = bn[nt];
    }
  }
  int cbase = wc * 7 * 16 + (lane & 15);
  #pragma unroll
  for (int nt = 0; nt < 7; ++nt) {
    int c = cbase + nt * 16;
    int o = c >> 1;
    bool isre = !(c & 1);
    if (o < HID) {
      _Float16* outp = Aout + (isre ? o : 208 + o);
      #pragma unroll
      for (int rt = 0; rt < 2; ++rt)
        #pragma unroll
        for (int q = 0; q < 4; ++q) {
          float v = acc[rt][nt][q];
          if (isre) v = fmaxf(v, 0.f);
          outp[(size_t)(wr * 32 + rt * 16 + g * 4 + q) * AST] = (_Float16)v;
        }
    }
  }
}

__global__ __launch_bounds__(512, 2) void k_mlp_mfma(
    const float2* __restrict__ Vcur, const float2* __restrict__ Z2,
    const _Float16* __restrict__ Bp,
    const float* __restrict__ W4re, const float* __restrict__ W4im,
    const float* __restrict__ b4re,
    float2* __restrict__ Vout) {
  int b = blockIdx.x;
  int tid = threadIdx.x;
  int wave = tid >> 6, lane = tid & 63;
  int wr = wave >> 2, wc = wave & 3;

  __shared__ _Float16 A0[64 * AST0];
  __shared__ _Float16 Abuf[2][64 * AST];
  __shared__ float2 Zs[64][16];
  __shared__ float2 Z2s[64][16];
  __shared__ float w4s[2][HID];
  __shared__ float stepv[64];
  __shared__ float scs[8];

  for (int idx = tid; idx < 1024; idx += 512) {
    ((float2*)Zs)[idx]  = Vcur[(size_t)b * 1024 + idx];
    ((float2*)Z2s)[idx] = Z2[(size_t)b * 1024 + idx];
  }
  for (int idx = tid; idx < HID; idx += 512) {
    w4s[0][idx] = W4re[idx];
    w4s[1][idx] = W4im[idx];
  }
  __syncthreads();

  for (int idx = tid; idx < 64 * AST0; idx += 512) {
    int m = idx / AST0, c = idx % AST0;
    float v;
    if (c < 64) {
      int f = c & 31;
      float2 z = (f < 16) ? Zs[m][f] : Z2s[m][f - 16];
      v = (c >= 32) ? z.y : z.x;
    } else v = (c == 64) ? 1.f : 0.f;
    A0[m * AST0 + c] = (_Float16)v;
  }
  for (int idx = tid; idx < 2 * 64 * 16; idx += 512) {
    int buf = idx >> 10, rem = idx & 1023, m = rem >> 4, p = rem & 15;
    int c = (p < 8) ? (200 + p) : (400 + p);
    Abuf[buf][m * AST + c] = (p == 7) ? (_Float16)1.f : (_Float16)0.f;
  }
  __syncthreads();

  do_gemm<AST0, B1_KC>(A0, Bp, &Abuf[0][0], wr, wc, lane);
  __syncthreads();
  do_gemm<AST, B23_KC>(&Abuf[0][0], Bp + B1_HALVES, &Abuf[1][0], wr, wc, lane);
  __syncthreads();
  do_gemm<AST, B23_KC>(&Abuf[1][0], Bp + B1_HALVES + B23_HALVES, &Abuf[0][0], wr, wc, lane);
  __syncthreads();

  {
    int m = tid >> 3, q = tid & 7;
    float acc = 0.f;
    for (int o = q; o < HID; o += 8) {
      float hr = (float)Abuf[0][m * AST + o];
      float hi = (float)Abuf[0][m * AST + 208 + o];
      acc += hr * w4s[0][o] - hi * w4s[1][o];
    }
    acc += __shfl_down(acc, 4, 8);
    acc += __shfl_down(acc, 2, 8);
    acc += __shfl_down(acc, 1, 8);
    if (q == 0) stepv[m] = acc + b4re[0];
  }
  __syncthreads();

  for (int idx = tid; idx < 1024; idx += 512) {
    int m = idx >> 4, f = idx & 15;
    float st = stepv[m];
    float2 z = Zs[m][f], z2 = Z2s[m][f];
    Zs[m][f] = make_float2(fmaf(st, z2.x, z.x), fmaf(st, z2.y, z.y));
  }
  __syncthreads();

  {
    const float2* vp = &Zs[wave * 8][0];
    float2 v0 = vp[lane * 2], v1 = vp[lane * 2 + 1];
    float p = v0.x * v0.x + v0.y * v0.y + v1.x * v1.x + v1.y * v1.y;
    p += __shfl_down(p, 32); p += __shfl_down(p, 16); p += __shfl_down(p, 8);
    p += __shfl_down(p, 4);  p += __shfl_down(p, 2);  p += __shfl_down(p, 1);
    if (lane == 0) scs[wave] = (p > PP) ? sqrtf(PP / p) : 1.f;
  }
  __syncthreads();
  for (int idx = tid; idx < 1024; idx += 512) {
    float sc = scs[idx >> 7];
    float2 v = ((float2*)Zs)[idx];
    Vout[(size_t)b * 1024 + idx] = make_float2(v.x * sc, v.y * sc);
  }
}

// ---------------- launch ----------------
extern "C" void kernel_launch(void* const* d_in, const int* in_sizes, int n_in,
                              void* d_out, int out_size, void* d_ws, size_t ws_size,
                              hipStream_t stream) {
  const float* Hre  = (const float*)d_in[0];
  const float* Him  = (const float*)d_in[1];
  const float* Vre  = (const float*)d_in[2];
  const float* Vim  = (const float*)d_in[3];
  const float* w    = (const float*)d_in[4];
  const float* W1re = (const float*)d_in[5];
  const float* W1im = (const float*)d_in[6];
  const float* b1re = (const float*)d_in[7];
  const float* b1im = (const float*)d_in[8];
  const float* W2re = (const float*)d_in[9];
  const float* W2im = (const float*)d_in[10];
  const float* b2re = (const float*)d_in[11];
  const float* b2im = (const float*)d_in[12];
  const float* W3re = (const float*)d_in[13];
  const float* W3im = (const float*)d_in[14];
  const float* b3re = (const float*)d_in[15];
  const float* b3im = (const float*)d_in[16];
  const float* W4re = (const float*)d_in[17];
  const float* W4im = (const float*)d_in[18];
  const float* b4re = (const float*)d_in[19];

  const size_t NV = (size_t)NS * BS * UU * NT * DD;   // 229376
  const size_t NB = (size_t)NS * BS * UU;             // 14336
  float2* Vcur = (float2*)d_ws;
  float2* Z2b  = Vcur + NV;
  float2* Yb   = Z2b + NV;
  float2* IGb  = Yb + NB * 8;
  _Float16* Bpack = (_Float16*)(IGb + NB * 4);

  k_pack<<<609, 256, 0, stream>>>(W1re, W1im, b1re, b1im, W2re, W2im, b2re, b2im,
                                  W3re, W3im, b3re, b3im, Bpack);
  k_norm0<<<NS * BS, 128, 0, stream>>>(Vre, Vim, Vcur);
  for (int it = 0; it < 3; ++it) {
    k_hv<<<NS * BS, 256, 0, stream>>>(Hre, Him, Vcur, Yb, IGb);
    k_stage2<<<NS * BS, 256, 0, stream>>>(Hre, Him, Vcur, Yb, IGb, w, Z2b);
    float2* vout = (it == 2) ? (float2*)d_out : Vcur;
    k_mlp_mfma<<<NS * BS / 8, 512, 0, stream>>>(Vcur, Z2b,
        Bpack + (size_t)it * BITER_HALVES,
        W4re + it * HID, W4im + it * HID, b4re + it, vout);
  }
}

// Round 7
// 258.642 us; speedup vs baseline: 5.2651x; 1.0437x over previous
//
#include <hip/hip_runtime.h>
#include <math.h>

#define NS 256
#define BS 7
#define UU 8
#define NR 4
#define NT 8
#define DD 2
#define HID 200
#define CIN 32
#define PP 100.0f
#define NOISEF 1e-7f

typedef _Float16 f16x8 __attribute__((ext_vector_type(8)));
typedef float f32x4 __attribute__((ext_vector_type(4)));

#define AST 424      // big activation buffer row stride (halves)
#define AST0 104     // layer-1 input stride (halves)
#define NTILES 28
#define B1_KC 3
#define B23_KC 13
#define B1_HALVES (B1_KC*NTILES*64*8)
#define B23_HALVES (B23_KC*NTILES*64*8)
#define BITER_HALVES (B1_HALVES + 2*B23_HALVES)

// ---------------- 4x4 complex Hermitian PD solve, 2 RHS (Cholesky) ----------------
__device__ void chol_solve(const float2 (*A)[NR], const float2 (*B)[DD], float2 (*X)[DD]) {
  float2 L[NR][NR];
  for (int j = 0; j < NR; ++j) {
    float d = A[j][j].x;
    for (int k = 0; k < j; ++k) d -= L[j][k].x * L[j][k].x + L[j][k].y * L[j][k].y;
    float ld = sqrtf(fmaxf(d, 1e-30f));
    L[j][j] = make_float2(ld, 0.f);
    float inv = 1.f / ld;
    for (int i = j + 1; i < NR; ++i) {
      float sr = A[i][j].x, si = A[i][j].y;
      for (int k = 0; k < j; ++k) {
        float2 a = L[i][k], b = L[j][k];
        sr -= a.x * b.x + a.y * b.y;
        si -= a.y * b.x - a.x * b.y;
      }
      L[i][j] = make_float2(sr * inv, si * inv);
    }
  }
  for (int c = 0; c < DD; ++c) {
    float2 z[NR];
    for (int i = 0; i < NR; ++i) {
      float sr = B[i][c].x, si = B[i][c].y;
      for (int k = 0; k < i; ++k) {
        float2 a = L[i][k], zz = z[k];
        sr -= a.x * zz.x - a.y * zz.y;
        si -= a.x * zz.y + a.y * zz.x;
      }
      float inv = 1.f / L[i][i].x;
      z[i] = make_float2(sr * inv, si * inv);
    }
    for (int i = NR - 1; i >= 0; --i) {
      float sr = z[i].x, si = z[i].y;
      for (int k = i + 1; k < NR; ++k) {
        float2 a = L[k][i], xx = X[k][c];
        sr -= a.x * xx.x + a.y * xx.y;
        si -= a.x * xx.y - a.y * xx.x;
      }
      float inv = 1.f / L[i][i].x;
      X[i][c] = make_float2(sr * inv, si * inv);
    }
  }
}

// ---------------- K0: initial power normalization ----------------
__global__ void k_norm0(const float* __restrict__ Vre, const float* __restrict__ Vim,
                        float2* __restrict__ Vcur) {
  int nl = blockIdx.x;
  int tid = threadIdx.x;
  size_t base = (size_t)nl * 128;
  float re = Vre[base + tid], im = Vim[base + tid];
  float p = re * re + im * im;
  p += __shfl_down(p, 32); p += __shfl_down(p, 16); p += __shfl_down(p, 8);
  p += __shfl_down(p, 4);  p += __shfl_down(p, 2);  p += __shfl_down(p, 1);
  __shared__ float sred[2];
  if ((tid & 63) == 0) sred[tid >> 6] = p;
  __syncthreads();
  float fro = sred[0] + sred[1];
  float sc = sqrtf(PP / fro);
  Vcur[base + tid] = make_float2(re * sc, im * sc);
}

// ---------------- k_hv v2: register-fused HV+Gram, 512 thr, wave=i (0..7), lane=(k,j) ----------------
__global__ __launch_bounds__(512) void k_hv(const float* __restrict__ Hre,
    const float* __restrict__ Him, const float2* __restrict__ Vcur,
    float2* __restrict__ Yb, float2* __restrict__ IGb) {
  int nl = blockIdx.x; int l = nl % BS; int n = nl / BS;
  int tid = threadIdx.x;
  int wave = tid >> 6;           // = i, 0..7  (512 threads = 8 waves)
  int lane = tid & 63;
  int k = lane >> 3, j = lane & 7;   // lanes 56-63 (k==7) idle

  __shared__ float2 Hs[1820];    // k*260 + i*32 + r*8 + t
  __shared__ float2 Vs[952];     // (k*8+j)*17 + t*2 + d
  __shared__ float2 GsL[8][10];  // reduced Gram (upper tri)
  __shared__ float2 TdL[8][10];  // diag-lane Gram contribution
  __shared__ float2 HV2L[8][8];

  for (int idx = tid; idx < 1792; idx += 512) {
    int kk = idx >> 8, irt = idx & 255;
    size_t off = ((size_t)(n * BS + kk) * BS + l) * 256 + irt;
    Hs[kk * 260 + irt] = make_float2(Hre[off], Him[off]);
  }
  const float2* Vn = Vcur + (size_t)n * 896;
  for (int idx = tid; idx < 896; idx += 512) {
    int kj = idx >> 4, td = idx & 15;
    Vs[kj * 17 + td] = Vn[idx];
  }
  __syncthreads();

  float2 Gu[10];
  #pragma unroll
  for (int q = 0; q < 10; ++q) Gu[q] = make_float2(0.f, 0.f);
  float2 hv[4][2];
  #pragma unroll
  for (int r = 0; r < 4; ++r)
    #pragma unroll
    for (int d = 0; d < 2; ++d) hv[r][d] = make_float2(0.f, 0.f);

  if (k < 7) {
    float2 v[8][2];
    const float2* vp = &Vs[(k * 8 + j) * 17];
    #pragma unroll
    for (int t = 0; t < 8; ++t) { v[t][0] = vp[2 * t]; v[t][1] = vp[2 * t + 1]; }
    #pragma unroll
    for (int r = 0; r < 4; ++r) {
      const float2* hp = &Hs[k * 260 + wave * 32 + r * 8];
      #pragma unroll
      for (int t = 0; t < 8; ++t) {
        float2 h = hp[t];
        #pragma unroll
        for (int d = 0; d < 2; ++d) {
          hv[r][d].x += h.x * v[t][d].x - h.y * v[t][d].y;
          hv[r][d].y += h.x * v[t][d].y + h.y * v[t][d].x;
        }
      }
    }
    int ui = 0;
    #pragma unroll
    for (int r = 0; r < 4; ++r)
      #pragma unroll
      for (int s = r; s < 4; ++s) {
        float gr = 0.f, gi = 0.f;
        #pragma unroll
        for (int d = 0; d < 2; ++d) {
          float2 a = hv[r][d], c = hv[s][d];
          gr += a.x * c.x + a.y * c.y;
          gi += a.y * c.x - a.x * c.y;
        }
        Gu[ui] = make_float2(gr, gi);
        ++ui;
      }
  }
  // diag lane (k==l, j==i): its Gram partial IS Td, its hv IS HV2 — stash pre-reduction
  if (k == l && j == wave) {
    #pragma unroll
    for (int q = 0; q < 10; ++q) TdL[wave][q] = Gu[q];
    #pragma unroll
    for (int r = 0; r < 4; ++r)
      #pragma unroll
      for (int d = 0; d < 2; ++d)
        HV2L[wave][r * 2 + d] = hv[r][d];
  }
  // butterfly reduce 20 floats over 64 lanes
  #pragma unroll
  for (int m = 1; m < 64; m <<= 1) {
    #pragma unroll
    for (int q = 0; q < 10; ++q) {
      Gu[q].x += __shfl_xor(Gu[q].x, m);
      Gu[q].y += __shfl_xor(Gu[q].y, m);
    }
  }
  if (lane == 0) {
    #pragma unroll
    for (int q = 0; q < 10; ++q) GsL[wave][q] = Gu[q];
  }
  __syncthreads();

  // 16 solves: tid 0-7 -> Usum->Y; tid 8-15 -> F->IG
  if (tid < 16) {
    int i = tid & 7, which = tid >> 3;
    float2 M[NR][NR];
    int ui = 0;
    #pragma unroll
    for (int r = 0; r < 4; ++r)
      #pragma unroll
      for (int s = r; s < 4; ++s) {
        float2 g = GsL[i][ui];
        if (which) { float2 td = TdL[i][ui]; g.x -= td.x; g.y -= td.y; }
        ++ui;
        M[r][s] = g;
        M[s][r] = make_float2(g.x, -g.y);
      }
    #pragma unroll
    for (int r = 0; r < 4; ++r) { M[r][r].x += NOISEF; M[r][r].y = 0.f; }
    float2 Bv[NR][DD], X[NR][DD];
    #pragma unroll
    for (int x = 0; x < 8; ++x) Bv[x >> 1][x & 1] = HV2L[i][x];
    chol_solve(M, Bv, X);
    size_t b = (size_t)nl * 8 + i;
    if (!which) {
      #pragma unroll
      for (int x = 0; x < 8; ++x) Yb[b * 8 + x] = X[x >> 1][x & 1];
    } else {
      #pragma unroll
      for (int d = 0; d < DD; ++d)
        #pragma unroll
        for (int e = 0; e < DD; ++e) {
          float gr = (d == e) ? 1.f : 0.f, gi = 0.f;
          #pragma unroll
          for (int r = 0; r < NR; ++r) {
            float2 a = Bv[r][d], x = X[r][e];
            gr += a.x * x.x + a.y * x.y;
            gi += a.x * x.y - a.y * x.x;
          }
          IGb[b * 4 + d * 2 + e] = make_float2(gr, gi);
        }
    }
  }
}

// ---------------- k_stage2: block per (n,l): A, B=A*IG, L, Lam -> Z2 ----------------
__global__ __launch_bounds__(256) void k_stage2(const float* __restrict__ Hre,
    const float* __restrict__ Him, const float2* __restrict__ Vcur,
    const float2* __restrict__ Yb, const float2* __restrict__ IGb,
    const float* __restrict__ w, float2* __restrict__ Z2out) {
  int nl = blockIdx.x; int l = nl % BS; int n = nl / BS;
  int tid = threadIdx.x;
  __shared__ float2 SM[3686];
  float2* Hsm  = SM;
  float2* Bsm  = SM;
  float2* Lsm  = SM + 952;
  float2* Ysm  = SM + 1792;
  float2* IGsm = SM + 2247;
  float2* Asm  = SM + 2478;
  float2* Lamm = SM + 3430;
  float2* Zlm  = SM + 3558;

  size_t hbase = ((size_t)n * BS + l) * 1792;
  for (int idx = tid; idx < 1792; idx += 256) {
    int t = idx & 7, r = (idx >> 3) & 3, u = (idx >> 5) & 7, m = idx >> 8;
    Hsm[((u * 4 + r) * 7 + m) * 8 + t] = make_float2(Hre[hbase + idx], Him[hbase + idx]);
  }
  const float2* yp = Yb + (size_t)n * 448;
  for (int idx = tid; idx < 448; idx += 256)
    Ysm[(idx >> 6) * 65 + (idx & 63)] = yp[idx];
  const float2* igp = IGb + (size_t)n * 224;
  if (tid < 224) IGsm[(tid >> 5) * 33 + (tid & 31)] = igp[tid];
  const float2* zp = Vcur + (size_t)nl * 128;
  if (tid < 128) Zlm[tid] = zp[tid];
  __syncthreads();

  for (int idx = tid; idx < 896; idx += 256) {
    int u = idx / 112, rem = idx % 112, m = rem >> 4, t = (rem >> 1) & 7, d = rem & 1;
    float ar = 0.f, ai = 0.f;
    #pragma unroll
    for (int r = 0; r < NR; ++r) {
      float2 h = Hsm[((u * 4 + r) * 7 + m) * 8 + t];
      float2 y = Ysm[m * 65 + u * 8 + r * 2 + d];
      ar += h.x * y.x + h.y * y.y;
      ai += h.x * y.y - h.y * y.x;
    }
    Asm[u * 119 + m * 17 + t * 2 + d] = make_float2(ar, ai);
  }
  __syncthreads();

  for (int idx = tid; idx < 896; idx += 256) {
    int u = idx / 112, rem = idx % 112, m = rem >> 4, t = (rem >> 1) & 7, e = rem & 1;
    float br = 0.f, bi = 0.f;
    #pragma unroll
    for (int d = 0; d < DD; ++d) {
      float2 a = Asm[u * 119 + m * 17 + t * 2 + d];
      float2 g = IGsm[m * 33 + u * 4 + d * 2 + e];
      br += a.x * g.x - a.y * g.y;
      bi += a.x * g.y + a.y * g.x;
    }
    Bsm[u * 119 + m * 17 + t * 2 + e] = make_float2(br, bi);
  }
  __syncthreads();

  for (int idx = tid; idx < 512; idx += 256) {
    int u = idx >> 6, t = (idx >> 3) & 7, s = idx & 7;
    float lr = 0.f, li = 0.f;
    #pragma unroll
    for (int m = 0; m < BS; ++m)
      #pragma unroll
      for (int e = 0; e < DD; ++e) {
        float2 bb = Bsm[u * 119 + m * 17 + t * 2 + e];
        float2 ac = Asm[u * 119 + m * 17 + s * 2 + e];
        lr += bb.x * ac.x + bb.y * ac.y;
        li += bb.y * ac.x - bb.x * ac.y;
      }
    float wu = w[u];
    Lsm[(u * 8 + t) * 8 + s] = make_float2(lr * wu, li * wu);
  }
  if (tid < 128) {
    int u = tid >> 4, t = (tid >> 1) & 7, e = tid & 1;
    float ar = 0.f, ai = 0.f;
    #pragma unroll
    for (int d = 0; d < DD; ++d) {
      float2 a = Asm[u * 119 + l * 17 + t * 2 + d];
      float2 g = IGsm[l * 33 + u * 4 + d * 2 + e];
      ar += a.x * g.x - a.y * g.y;
      ai += a.x * g.y + a.y * g.x;
    }
    float wu = w[u];
    Lamm[u * 16 + t * 2 + e] = make_float2(ar * wu, ai * wu);
  }
  __syncthreads();

  if (tid < 128) {
    int u = tid >> 4, t = (tid >> 1) & 7, d = tid & 1;
    float2 lam = Lamm[u * 16 + t * 2 + d];
    float zr = lam.x, zi = lam.y;
    #pragma unroll
    for (int s = 0; s < NT; ++s) {
      float2 Lts = Lsm[(u * 8 + t) * 8 + s];
      float2 z = Zlm[u * 16 + s * 2 + d];
      zr -= Lts.x * z.x - Lts.y * z.y;
      zi -= Lts.x * z.y + Lts.y * z.x;
    }
    Z2out[(size_t)nl * 128 + u * 16 + t * 2 + d] = make_float2(zr, zi);
  }
}

// ---------------- Bpack ----------------
__global__ __launch_bounds__(256) void k_pack(
    const float* __restrict__ W1re, const float* __restrict__ W1im,
    const float* __restrict__ b1re, const float* __restrict__ b1im,
    const float* __restrict__ W2re, const float* __restrict__ W2im,
    const float* __restrict__ b2re, const float* __restrict__ b2im,
    const float* __restrict__ W3re, const float* __restrict__ W3im,
    const float* __restrict__ b3re, const float* __restrict__ b3im,
    _Float16* __restrict__ Bout) {
  int gid = blockIdx.x * 256 + threadIdx.x;
  int lane = gid & 63;
  int rest = gid >> 6;
  int nt = rest % NTILES;
  int id2 = rest / NTILES;
  if (id2 >= 87) return;
  int iter = id2 / 29, kk = id2 % 29;
  int layer, kc;
  if (kk < 3)       { layer = 0; kc = kk; }
  else if (kk < 16) { layer = 1; kc = kk - 3; }
  else              { layer = 2; kc = kk - 16; }
  const float *Wr, *Wi, *br, *bi;
  if (layer == 0) { Wr = W1re + iter*HID*CIN; Wi = W1im + iter*HID*CIN; br = b1re + iter*HID; bi = b1im + iter*HID; }
  else if (layer == 1) { Wr = W2re + iter*HID*HID; Wi = W2im + iter*HID*HID; br = b2re + iter*HID; bi = b2im + iter*HID; }
  else { Wr = W3re + iter*HID*HID; Wi = W3im + iter*HID*HID; br = b3re + iter*HID; bi = b3im + iter*HID; }
  int c = nt * 16 + (lane & 15);
  int o = c >> 1; int odd = c & 1;
  f16x8 frag;
  #pragma unroll
  for (int j = 0; j < 8; ++j) {
    int k = kc * 32 + (lane >> 4) * 8 + j;
    float v = 0.f;
    if (o < HID) {
      if (layer == 0) {
        if (k < 32)       v = odd ? Wi[o*32 + k] : Wr[o*32 + k];
        else if (k < 64)  { int i = k - 32; v = odd ? Wr[o*32 + i] : -Wi[o*32 + i]; }
        else if (k == 64) v = odd ? bi[o] : br[o];
      } else {
        if (k < 200)       v = odd ? Wi[o*200 + k] : Wr[o*200 + k];
        else if (k == 207) v = odd ? bi[o] : br[o];
        else if (k >= 208 && k < 408) { int i = k - 208; v = odd ? Wr[o*200 + i] : -Wi[o*200 + i]; }
      }
    }
    frag[j] = (_Float16)v;
  }
  size_t off = (size_t)iter * BITER_HALVES
             + (layer == 0 ? 0 : (layer == 1 ? B1_HALVES : (B1_HALVES + B23_HALVES)))
             + ((size_t)(kc * NTILES + nt) * 64 + lane) * 8;
  *(f16x8*)(Bout + off) = frag;
}

// ---------------- fused MFMA MLP (8 waves: 2 row x 4 col) — round-4 version ----------------
template<int ASTRIDE, int KC>
__device__ inline void do_gemm(const _Float16* Ain,
                               const _Float16* __restrict__ Bg,
                               _Float16* Aout, int wr, int wc, int lane) {
  f32x4 acc[2][7];
  #pragma unroll
  for (int rt = 0; rt < 2; ++rt)
    #pragma unroll
    for (int nt = 0; nt < 7; ++nt)
      acc[rt][nt] = (f32x4){0.f, 0.f, 0.f, 0.f};
  const int r0 = (lane & 15) + wr * 32, g = lane >> 4;
  const _Float16* bp0 = Bg + ((size_t)(wc * 7) * 64 + lane) * 8;
  f16x8 b[7];
  #pragma unroll
  for (int nt = 0; nt < 7; ++nt) b[nt] = *(const f16x8*)(bp0 + nt * 512);
  f16x8 a0 = *(const f16x8*)(Ain + r0 * ASTRIDE + 8 * g);
  f16x8 a1 = *(const f16x8*)(Ain + (r0 + 16) * ASTRIDE + 8 * g);
  #pragma unroll
  for (int kc = 0; kc < KC; ++kc) {
    f16x8 a0n, a1n, bn[7];
    if (kc + 1 < KC) {
      const _Float16* bpn = bp0 + (size_t)(kc + 1) * (NTILES * 512);
      #pragma unroll
      for (int nt = 0; nt < 7; ++nt) bn[nt] = *(const f16x8*)(bpn + nt * 512);
      a0n = *(const f16x8*)(Ain + r0 * ASTRIDE + (kc + 1) * 32 + 8 * g);
      a1n = *(const f16x8*)(Ain + (r0 + 16) * ASTRIDE + (kc + 1) * 32 + 8 * g);
    }
    #pragma unroll
    for (int nt = 0; nt < 7; ++nt) {
      acc[0][nt] = __builtin_amdgcn_mfma_f32_16x16x32_f16(a0, b[nt], acc[0][nt], 0, 0, 0);
      acc[1][nt] = __builtin_amdgcn_mfma_f32_16x16x32_f16(a1, b[nt], acc[1][nt], 0, 0, 0);
    }
    if (kc + 1 < KC) {
      a0 = a0n; a1 = a1n;
      #pragma unroll
      for (int nt = 0; nt < 7; ++nt) b[nt] = bn[nt];
    }
  }
  int cbase = wc * 7 * 16 + (lane & 15);
  #pragma unroll
  for (int nt = 0; nt < 7; ++nt) {
    int c = cbase + nt * 16;
    int o = c >> 1;
    bool isre = !(c & 1);
    if (o < HID) {
      _Float16* outp = Aout + (isre ? o : 208 + o);
      #pragma unroll
      for (int rt = 0; rt < 2; ++rt)
        #pragma unroll
        for (int q = 0; q < 4; ++q) {
          float v = acc[rt][nt][q];
          if (isre) v = fmaxf(v, 0.f);
          outp[(size_t)(wr * 32 + rt * 16 + g * 4 + q) * AST] = (_Float16)v;
        }
    }
  }
}

__global__ __launch_bounds__(512, 2) void k_mlp_mfma(
    const float2* __restrict__ Vcur, const float2* __restrict__ Z2,
    const _Float16* __restrict__ Bp,
    const float* __restrict__ W4re, const float* __restrict__ W4im,
    const float* __restrict__ b4re,
    float2* __restrict__ Vout) {
  int b = blockIdx.x;
  int tid = threadIdx.x;
  int wave = tid >> 6, lane = tid & 63;
  int wr = wave >> 2, wc = wave & 3;

  __shared__ _Float16 A0[64 * AST0];
  __shared__ _Float16 Abuf[2][64 * AST];
  __shared__ float2 Zs[64][16];
  __shared__ float2 Z2s[64][16];
  __shared__ float w4s[2][HID];
  __shared__ float stepv[64];
  __shared__ float scs[8];

  for (int idx = tid; idx < 1024; idx += 512) {
    ((float2*)Zs)[idx]  = Vcur[(size_t)b * 1024 + idx];
    ((float2*)Z2s)[idx] = Z2[(size_t)b * 1024 + idx];
  }
  for (int idx = tid; idx < HID; idx += 512) {
    w4s[0][idx] = W4re[idx];
    w4s[1][idx] = W4im[idx];
  }
  __syncthreads();

  for (int idx = tid; idx < 64 * AST0; idx += 512) {
    int m = idx / AST0, c = idx % AST0;
    float v;
    if (c < 64) {
      int f = c & 31;
      float2 z = (f < 16) ? Zs[m][f] : Z2s[m][f - 16];
      v = (c >= 32) ? z.y : z.x;
    } else v = (c == 64) ? 1.f : 0.f;
    A0[m * AST0 + c] = (_Float16)v;
  }
  for (int idx = tid; idx < 2 * 64 * 16; idx += 512) {
    int buf = idx >> 10, rem = idx & 1023, m = rem >> 4, p = rem & 15;
    int c = (p < 8) ? (200 + p) : (400 + p);
    Abuf[buf][m * AST + c] = (p == 7) ? (_Float16)1.f : (_Float16)0.f;
  }
  __syncthreads();

  do_gemm<AST0, B1_KC>(A0, Bp, &Abuf[0][0], wr, wc, lane);
  __syncthreads();
  do_gemm<AST, B23_KC>(&Abuf[0][0], Bp + B1_HALVES, &Abuf[1][0], wr, wc, lane);
  __syncthreads();
  do_gemm<AST, B23_KC>(&Abuf[1][0], Bp + B1_HALVES + B23_HALVES, &Abuf[0][0], wr, wc, lane);
  __syncthreads();

  {
    int m = tid >> 3, q = tid & 7;
    float acc = 0.f;
    for (int o = q; o < HID; o += 8) {
      float hr = (float)Abuf[0][m * AST + o];
      float hi = (float)Abuf[0][m * AST + 208 + o];
      acc += hr * w4s[0][o] - hi * w4s[1][o];
    }
    acc += __shfl_down(acc, 4, 8);
    acc += __shfl_down(acc, 2, 8);
    acc += __shfl_down(acc, 1, 8);
    if (q == 0) stepv[m] = acc + b4re[0];
  }
  __syncthreads();

  for (int idx = tid; idx < 1024; idx += 512) {
    int m = idx >> 4, f = idx & 15;
    float st = stepv[m];
    float2 z = Zs[m][f], z2 = Z2s[m][f];
    Zs[m][f] = make_float2(fmaf(st, z2.x, z.x), fmaf(st, z2.y, z.y));
  }
  __syncthreads();

  {
    const float2* vp = &Zs[wave * 8][0];
    float2 v0 = vp[lane * 2], v1 = vp[lane * 2 + 1];
    float p = v0.x * v0.x + v0.y * v0.y + v1.x * v1.x + v1.y * v1.y;
    p += __shfl_down(p, 32); p += __shfl_down(p, 16); p += __shfl_down(p, 8);
    p += __shfl_down(p, 4);  p += __shfl_down(p, 2);  p += __shfl_down(p, 1);
    if (lane == 0) scs[wave] = (p > PP) ? sqrtf(PP / p) : 1.f;
  }
  __syncthreads();
  for (int idx = tid; idx < 1024; idx += 512) {
    float sc = scs[idx >> 7];
    float2 v = ((float2*)Zs)[idx];
    Vout[(size_t)b * 1024 + idx] = make_float2(v.x * sc, v.y * sc);
  }
}

// ---------------- launch ----------------
extern "C" void kernel_launch(void* const* d_in, const int* in_sizes, int n_in,
                              void* d_out, int out_size, void* d_ws, size_t ws_size,
                              hipStream_t stream) {
  const float* Hre  = (const float*)d_in[0];
  const float* Him  = (const float*)d_in[1];
  const float* Vre  = (const float*)d_in[2];
  const float* Vim  = (const float*)d_in[3];
  const float* w    = (const float*)d_in[4];
  const float* W1re = (const float*)d_in[5];
  const float* W1im = (const float*)d_in[6];
  const float* b1re = (const float*)d_in[7];
  const float* b1im = (const float*)d_in[8];
  const float* W2re = (const float*)d_in[9];
  const float* W2im = (const float*)d_in[10];
  const float* b2re = (const float*)d_in[11];
  const float* b2im = (const float*)d_in[12];
  const float* W3re = (const float*)d_in[13];
  const float* W3im = (const float*)d_in[14];
  const float* b3re = (const float*)d_in[15];
  const float* b3im = (const float*)d_in[16];
  const float* W4re = (const float*)d_in[17];
  const float* W4im = (const float*)d_in[18];
  const float* b4re = (const float*)d_in[19];

  const size_t NV = (size_t)NS * BS * UU * NT * DD;   // 229376
  const size_t NB = (size_t)NS * BS * UU;             // 14336
  float2* Vcur = (float2*)d_ws;
  float2* Z2b  = Vcur + NV;
  float2* Yb   = Z2b + NV;
  float2* IGb  = Yb + NB * 8;
  _Float16* Bpack = (_Float16*)(IGb + NB * 4);

  k_pack<<<609, 256, 0, stream>>>(W1re, W1im, b1re, b1im, W2re, W2im, b2re, b2im,
                                  W3re, W3im, b3re, b3im, Bpack);
  k_norm0<<<NS * BS, 128, 0, stream>>>(Vre, Vim, Vcur);
  for (int it = 0; it < 3; ++it) {
    k_hv<<<NS * BS, 512, 0, stream>>>(Hre, Him, Vcur, Yb, IGb);
    k_stage2<<<NS * BS, 256, 0, stream>>>(Hre, Him, Vcur, Yb, IGb, w, Z2b);
    float2* vout = (it == 2) ? (float2*)d_out : Vcur;
    k_mlp_mfma<<<NS * BS / 8, 512, 0, stream>>>(Vcur, Z2b,
        Bpack + (size_t)it * BITER_HALVES,
        W4re + it * HID, W4im + it * HID, b4re + it, vout);
  }
}

// Round 8
// 252.067 us; speedup vs baseline: 5.4024x; 1.0261x over previous
//
#include <hip/hip_runtime.h>
#include <math.h>

#define NS 256
#define BS 7
#define UU 8
#define NR 4
#define NT 8
#define DD 2
#define HID 200
#define CIN 32
#define PP 100.0f
#define NOISEF 1e-7f

typedef _Float16 f16x8 __attribute__((ext_vector_type(8)));
typedef float f32x4 __attribute__((ext_vector_type(4)));

#define AST 424      // big activation buffer row stride (halves)
#define AST0 104     // layer-1 input stride (halves)
#define NTILES 28
#define B1_KC 3
#define B23_KC 13
#define B1_HALVES (B1_KC*NTILES*64*8)
#define B23_HALVES (B23_KC*NTILES*64*8)
#define BITER_HALVES (B1_HALVES + 2*B23_HALVES)

// ---------------- 4x4 complex Hermitian PD solve, 2 RHS (Cholesky) ----------------
__device__ void chol_solve(const float2 (*A)[NR], const float2 (*B)[DD], float2 (*X)[DD]) {
  float2 L[NR][NR];
  for (int j = 0; j < NR; ++j) {
    float d = A[j][j].x;
    for (int k = 0; k < j; ++k) d -= L[j][k].x * L[j][k].x + L[j][k].y * L[j][k].y;
    float ld = sqrtf(fmaxf(d, 1e-30f));
    L[j][j] = make_float2(ld, 0.f);
    float inv = 1.f / ld;
    for (int i = j + 1; i < NR; ++i) {
      float sr = A[i][j].x, si = A[i][j].y;
      for (int k = 0; k < j; ++k) {
        float2 a = L[i][k], b = L[j][k];
        sr -= a.x * b.x + a.y * b.y;
        si -= a.y * b.x - a.x * b.y;
      }
      L[i][j] = make_float2(sr * inv, si * inv);
    }
  }
  for (int c = 0; c < DD; ++c) {
    float2 z[NR];
    for (int i = 0; i < NR; ++i) {
      float sr = B[i][c].x, si = B[i][c].y;
      for (int k = 0; k < i; ++k) {
        float2 a = L[i][k], zz = z[k];
        sr -= a.x * zz.x - a.y * zz.y;
        si -= a.x * zz.y + a.y * zz.x;
      }
      float inv = 1.f / L[i][i].x;
      z[i] = make_float2(sr * inv, si * inv);
    }
    for (int i = NR - 1; i >= 0; --i) {
      float sr = z[i].x, si = z[i].y;
      for (int k = i + 1; k < NR; ++k) {
        float2 a = L[k][i], xx = X[k][c];
        sr -= a.x * xx.x + a.y * xx.y;
        si -= a.x * xx.y - a.y * xx.x;
      }
      float inv = 1.f / L[i][i].x;
      X[i][c] = make_float2(sr * inv, si * inv);
    }
  }
}

// ---------------- K0: initial power normalization ----------------
__global__ void k_norm0(const float* __restrict__ Vre, const float* __restrict__ Vim,
                        float2* __restrict__ Vcur) {
  int nl = blockIdx.x;
  int tid = threadIdx.x;
  size_t base = (size_t)nl * 128;
  float re = Vre[base + tid], im = Vim[base + tid];
  float p = re * re + im * im;
  p += __shfl_down(p, 32); p += __shfl_down(p, 16); p += __shfl_down(p, 8);
  p += __shfl_down(p, 4);  p += __shfl_down(p, 2);  p += __shfl_down(p, 1);
  __shared__ float sred[2];
  if ((tid & 63) == 0) sred[tid >> 6] = p;
  __syncthreads();
  float fro = sred[0] + sred[1];
  float sc = sqrtf(PP / fro);
  Vcur[base + tid] = make_float2(re * sc, im * sc);
}

// ---------------- k_hv v3: register-fused HV+Gram, no solver tail ----------------
// 512 thr, wave=i (0..7), lane=(k,j). Outputs: Gsb[b][10], Tdb[b][10], HV2b[b][8].
__global__ __launch_bounds__(512) void k_hv(const float* __restrict__ Hre,
    const float* __restrict__ Him, const float2* __restrict__ Vcur,
    float2* __restrict__ Gsb, float2* __restrict__ Tdb, float2* __restrict__ HV2b) {
  int nl = blockIdx.x; int l = nl % BS; int n = nl / BS;
  int tid = threadIdx.x;
  int wave = tid >> 6;           // = i, 0..7
  int lane = tid & 63;
  int k = lane >> 3, j = lane & 7;   // lanes 56-63 (k==7) idle

  __shared__ float2 Hs[1820];    // k*260 + i*32 + r*8 + t
  __shared__ float2 Vs[952];     // (k*8+j)*17 + t*2 + d

  for (int idx = tid; idx < 1792; idx += 512) {
    int kk = idx >> 8, irt = idx & 255;
    size_t off = ((size_t)(n * BS + kk) * BS + l) * 256 + irt;
    Hs[kk * 260 + irt] = make_float2(Hre[off], Him[off]);
  }
  const float2* Vn = Vcur + (size_t)n * 896;
  for (int idx = tid; idx < 896; idx += 512) {
    int kj = idx >> 4, td = idx & 15;
    Vs[kj * 17 + td] = Vn[idx];
  }
  __syncthreads();

  float2 Gu[10];
  #pragma unroll
  for (int q = 0; q < 10; ++q) Gu[q] = make_float2(0.f, 0.f);
  float2 hv[4][2];
  #pragma unroll
  for (int r = 0; r < 4; ++r)
    #pragma unroll
    for (int d = 0; d < 2; ++d) hv[r][d] = make_float2(0.f, 0.f);

  if (k < 7) {
    float2 v[8][2];
    const float2* vp = &Vs[(k * 8 + j) * 17];
    #pragma unroll
    for (int t = 0; t < 8; ++t) { v[t][0] = vp[2 * t]; v[t][1] = vp[2 * t + 1]; }
    #pragma unroll
    for (int r = 0; r < 4; ++r) {
      const float2* hp = &Hs[k * 260 + wave * 32 + r * 8];
      #pragma unroll
      for (int t = 0; t < 8; ++t) {
        float2 h = hp[t];
        #pragma unroll
        for (int d = 0; d < 2; ++d) {
          hv[r][d].x += h.x * v[t][d].x - h.y * v[t][d].y;
          hv[r][d].y += h.x * v[t][d].y + h.y * v[t][d].x;
        }
      }
    }
    int ui = 0;
    #pragma unroll
    for (int r = 0; r < 4; ++r)
      #pragma unroll
      for (int s = r; s < 4; ++s) {
        float gr = 0.f, gi = 0.f;
        #pragma unroll
        for (int d = 0; d < 2; ++d) {
          float2 a = hv[r][d], c = hv[s][d];
          gr += a.x * c.x + a.y * c.y;
          gi += a.y * c.x - a.x * c.y;
        }
        Gu[ui] = make_float2(gr, gi);
        ++ui;
      }
  }
  // diag lane (k==l, j==i): its Gram partial IS Td, its hv IS HV2 — write pre-reduction
  if (k == l && j == wave) {
    float2* tdp = Tdb + (size_t)(nl * 8 + wave) * 10;
    #pragma unroll
    for (int q = 0; q < 10; ++q) tdp[q] = Gu[q];
    float2* h2p = HV2b + (size_t)(nl * 8 + wave) * 8;
    #pragma unroll
    for (int x = 0; x < 8; ++x) h2p[x] = hv[x >> 1][x & 1];
  }
  // butterfly reduce 20 floats over 64 lanes
  #pragma unroll
  for (int m = 1; m < 64; m <<= 1) {
    #pragma unroll
    for (int q = 0; q < 10; ++q) {
      Gu[q].x += __shfl_xor(Gu[q].x, m);
      Gu[q].y += __shfl_xor(Gu[q].y, m);
    }
  }
  if (lane == 0) {
    float2* gp = Gsb + (size_t)(nl * 8 + wave) * 10;
    #pragma unroll
    for (int q = 0; q < 10; ++q) gp[q] = Gu[q];
  }
}

// ---------------- k_solve: 1 thread per 4x4 solve, dense waves ----------------
// gid < 14336: Usum solve -> Y. gid >= 14336: F solve -> IG. 14336 = 56*256, so
// `which` is block-uniform (no divergence).
__global__ __launch_bounds__(256) void k_solve(const float2* __restrict__ Gsb,
    const float2* __restrict__ Tdb, const float2* __restrict__ HV2b,
    float2* __restrict__ Yb, float2* __restrict__ IGb) {
  int gid = blockIdx.x * 256 + threadIdx.x;      // 0..28671
  int which = (gid >= 14336) ? 1 : 0;
  int b = gid - which * 14336;

  float2 G[10];
  const float2* gp = Gsb + (size_t)b * 10;
  #pragma unroll
  for (int q = 0; q < 10; ++q) G[q] = gp[q];
  if (which) {
    const float2* tp = Tdb + (size_t)b * 10;
    #pragma unroll
    for (int q = 0; q < 10; ++q) { float2 t = tp[q]; G[q].x -= t.x; G[q].y -= t.y; }
  }
  float2 M[NR][NR];
  {
    int ui = 0;
    #pragma unroll
    for (int r = 0; r < 4; ++r)
      #pragma unroll
      for (int s = r; s < 4; ++s) {
        M[r][s] = G[ui];
        M[s][r] = make_float2(G[ui].x, -G[ui].y);
        ++ui;
      }
    #pragma unroll
    for (int r = 0; r < 4; ++r) { M[r][r].x += NOISEF; M[r][r].y = 0.f; }
  }
  float2 Bv[NR][DD], X[NR][DD];
  const float2* hp = HV2b + (size_t)b * 8;
  #pragma unroll
  for (int x = 0; x < 8; ++x) Bv[x >> 1][x & 1] = hp[x];
  chol_solve(M, Bv, X);
  if (!which) {
    #pragma unroll
    for (int x = 0; x < 8; ++x) Yb[(size_t)b * 8 + x] = X[x >> 1][x & 1];
  } else {
    #pragma unroll
    for (int d = 0; d < DD; ++d)
      #pragma unroll
      for (int e = 0; e < DD; ++e) {
        float gr = (d == e) ? 1.f : 0.f, gi = 0.f;
        #pragma unroll
        for (int r = 0; r < NR; ++r) {
          float2 a = Bv[r][d], x = X[r][e];
          gr += a.x * x.x + a.y * x.y;
          gi += a.x * x.y - a.y * x.x;
        }
        IGb[(size_t)b * 4 + d * 2 + e] = make_float2(gr, gi);
      }
  }
}

// ---------------- k_stage2: block per (n,l): A, B=A*IG, L, Lam -> Z2 ----------------
__global__ __launch_bounds__(256) void k_stage2(const float* __restrict__ Hre,
    const float* __restrict__ Him, const float2* __restrict__ Vcur,
    const float2* __restrict__ Yb, const float2* __restrict__ IGb,
    const float* __restrict__ w, float2* __restrict__ Z2out) {
  int nl = blockIdx.x; int l = nl % BS; int n = nl / BS;
  int tid = threadIdx.x;
  __shared__ float2 SM[3686];
  float2* Hsm  = SM;
  float2* Bsm  = SM;
  float2* Lsm  = SM + 952;
  float2* Ysm  = SM + 1792;
  float2* IGsm = SM + 2247;
  float2* Asm  = SM + 2478;
  float2* Lamm = SM + 3430;
  float2* Zlm  = SM + 3558;

  size_t hbase = ((size_t)n * BS + l) * 1792;
  for (int idx = tid; idx < 1792; idx += 256) {
    int t = idx & 7, r = (idx >> 3) & 3, u = (idx >> 5) & 7, m = idx >> 8;
    Hsm[((u * 4 + r) * 7 + m) * 8 + t] = make_float2(Hre[hbase + idx], Him[hbase + idx]);
  }
  const float2* yp = Yb + (size_t)n * 448;
  for (int idx = tid; idx < 448; idx += 256)
    Ysm[(idx >> 6) * 65 + (idx & 63)] = yp[idx];
  const float2* igp = IGb + (size_t)n * 224;
  if (tid < 224) IGsm[(tid >> 5) * 33 + (tid & 31)] = igp[tid];
  const float2* zp = Vcur + (size_t)nl * 128;
  if (tid < 128) Zlm[tid] = zp[tid];
  __syncthreads();

  for (int idx = tid; idx < 896; idx += 256) {
    int u = idx / 112, rem = idx % 112, m = rem >> 4, t = (rem >> 1) & 7, d = rem & 1;
    float ar = 0.f, ai = 0.f;
    #pragma unroll
    for (int r = 0; r < NR; ++r) {
      float2 h = Hsm[((u * 4 + r) * 7 + m) * 8 + t];
      float2 y = Ysm[m * 65 + u * 8 + r * 2 + d];
      ar += h.x * y.x + h.y * y.y;
      ai += h.x * y.y - h.y * y.x;
    }
    Asm[u * 119 + m * 17 + t * 2 + d] = make_float2(ar, ai);
  }
  __syncthreads();

  for (int idx = tid; idx < 896; idx += 256) {
    int u = idx / 112, rem = idx % 112, m = rem >> 4, t = (rem >> 1) & 7, e = rem & 1;
    float br = 0.f, bi = 0.f;
    #pragma unroll
    for (int d = 0; d < DD; ++d) {
      float2 a = Asm[u * 119 + m * 17 + t * 2 + d];
      float2 g = IGsm[m * 33 + u * 4 + d * 2 + e];
      br += a.x * g.x - a.y * g.y;
      bi += a.x * g.y + a.y * g.x;
    }
    Bsm[u * 119 + m * 17 + t * 2 + e] = make_float2(br, bi);
  }
  __syncthreads();

  for (int idx = tid; idx < 512; idx += 256) {
    int u = idx >> 6, t = (idx >> 3) & 7, s = idx & 7;
    float lr = 0.f, li = 0.f;
    #pragma unroll
    for (int m = 0; m < BS; ++m)
      #pragma unroll
      for (int e = 0; e < DD; ++e) {
        float2 bb = Bsm[u * 119 + m * 17 + t * 2 + e];
        float2 ac = Asm[u * 119 + m * 17 + s * 2 + e];
        lr += bb.x * ac.x + bb.y * ac.y;
        li += bb.y * ac.x - bb.x * ac.y;
      }
    float wu = w[u];
    Lsm[(u * 8 + t) * 8 + s] = make_float2(lr * wu, li * wu);
  }
  if (tid < 128) {
    int u = tid >> 4, t = (tid >> 1) & 7, e = tid & 1;
    float ar = 0.f, ai = 0.f;
    #pragma unroll
    for (int d = 0; d < DD; ++d) {
      float2 a = Asm[u * 119 + l * 17 + t * 2 + d];
      float2 g = IGsm[l * 33 + u * 4 + d * 2 + e];
      ar += a.x * g.x - a.y * g.y;
      ai += a.x * g.y + a.y * g.x;
    }
    float wu = w[u];
    Lamm[u * 16 + t * 2 + e] = make_float2(ar * wu, ai * wu);
  }
  __syncthreads();

  if (tid < 128) {
    int u = tid >> 4, t = (tid >> 1) & 7, d = tid & 1;
    float2 lam = Lamm[u * 16 + t * 2 + d];
    float zr = lam.x, zi = lam.y;
    #pragma unroll
    for (int s = 0; s < NT; ++s) {
      float2 Lts = Lsm[(u * 8 + t) * 8 + s];
      float2 z = Zlm[u * 16 + s * 2 + d];
      zr -= Lts.x * z.x - Lts.y * z.y;
      zi -= Lts.x * z.y + Lts.y * z.x;
    }
    Z2out[(size_t)nl * 128 + u * 16 + t * 2 + d] = make_float2(zr, zi);
  }
}

// ---------------- Bpack ----------------
__global__ __launch_bounds__(256) void k_pack(
    const float* __restrict__ W1re, const float* __restrict__ W1im,
    const float* __restrict__ b1re, const float* __restrict__ b1im,
    const float* __restrict__ W2re, const float* __restrict__ W2im,
    const float* __restrict__ b2re, const float* __restrict__ b2im,
    const float* __restrict__ W3re, const float* __restrict__ W3im,
    const float* __restrict__ b3re, const float* __restrict__ b3im,
    _Float16* __restrict__ Bout) {
  int gid = blockIdx.x * 256 + threadIdx.x;
  int lane = gid & 63;
  int rest = gid >> 6;
  int nt = rest % NTILES;
  int id2 = rest / NTILES;
  if (id2 >= 87) return;
  int iter = id2 / 29, kk = id2 % 29;
  int layer, kc;
  if (kk < 3)       { layer = 0; kc = kk; }
  else if (kk < 16) { layer = 1; kc = kk - 3; }
  else              { layer = 2; kc = kk - 16; }
  const float *Wr, *Wi, *br, *bi;
  if (layer == 0) { Wr = W1re + iter*HID*CIN; Wi = W1im + iter*HID*CIN; br = b1re + iter*HID; bi = b1im + iter*HID; }
  else if (layer == 1) { Wr = W2re + iter*HID*HID; Wi = W2im + iter*HID*HID; br = b2re + iter*HID; bi = b2im + iter*HID; }
  else { Wr = W3re + iter*HID*HID; Wi = W3im + iter*HID*HID; br = b3re + iter*HID; bi = b3im + iter*HID; }
  int c = nt * 16 + (lane & 15);
  int o = c >> 1; int odd = c & 1;
  f16x8 frag;
  #pragma unroll
  for (int j = 0; j < 8; ++j) {
    int k = kc * 32 + (lane >> 4) * 8 + j;
    float v = 0.f;
    if (o < HID) {
      if (layer == 0) {
        if (k < 32)       v = odd ? Wi[o*32 + k] : Wr[o*32 + k];
        else if (k < 64)  { int i = k - 32; v = odd ? Wr[o*32 + i] : -Wi[o*32 + i]; }
        else if (k == 64) v = odd ? bi[o] : br[o];
      } else {
        if (k < 200)       v = odd ? Wi[o*200 + k] : Wr[o*200 + k];
        else if (k == 207) v = odd ? bi[o] : br[o];
        else if (k >= 208 && k < 408) { int i = k - 208; v = odd ? Wr[o*200 + i] : -Wi[o*200 + i]; }
      }
    }
    frag[j] = (_Float16)v;
  }
  size_t off = (size_t)iter * BITER_HALVES
             + (layer == 0 ? 0 : (layer == 1 ? B1_HALVES : (B1_HALVES + B23_HALVES)))
             + ((size_t)(kc * NTILES + nt) * 64 + lane) * 8;
  *(f16x8*)(Bout + off) = frag;
}

// ---------------- fused MFMA MLP (8 waves: 2 row x 4 col) ----------------
template<int ASTRIDE, int KC>
__device__ inline void do_gemm(const _Float16* Ain,
                               const _Float16* __restrict__ Bg,
                               _Float16* Aout, int wr, int wc, int lane) {
  f32x4 acc[2][7];
  #pragma unroll
  for (int rt = 0; rt < 2; ++rt)
    #pragma unroll
    for (int nt = 0; nt < 7; ++nt)
      acc[rt][nt] = (f32x4){0.f, 0.f, 0.f, 0.f};
  const int r0 = (lane & 15) + wr * 32, g = lane >> 4;
  const _Float16* bp0 = Bg + ((size_t)(wc * 7) * 64 + lane) * 8;
  f16x8 b[7];
  #pragma unroll
  for (int nt = 0; nt < 7; ++nt) b[nt] = *(const f16x8*)(bp0 + nt * 512);
  f16x8 a0 = *(const f16x8*)(Ain + r0 * ASTRIDE + 8 * g);
  f16x8 a1 = *(const f16x8*)(Ain + (r0 + 16) * ASTRIDE + 8 * g);
  #pragma unroll
  for (int kc = 0; kc < KC; ++kc) {
    f16x8 a0n, a1n, bn[7];
    if (kc + 1 < KC) {
      const _Float16* bpn = bp0 + (size_t)(kc + 1) * (NTILES * 512);
      #pragma unroll
      for (int nt = 0; nt < 7; ++nt) bn[nt] = *(const f16x8*)(bpn + nt * 512);
      a0n = *(const f16x8*)(Ain + r0 * ASTRIDE + (kc + 1) * 32 + 8 * g);
      a1n = *(const f16x8*)(Ain + (r0 + 16) * ASTRIDE + (kc + 1) * 32 + 8 * g);
    }
    #pragma unroll
    for (int nt = 0; nt < 7; ++nt) {
      acc[0][nt] = __builtin_amdgcn_mfma_f32_16x16x32_f16(a0, b[nt], acc[0][nt], 0, 0, 0);
      acc[1][nt] = __builtin_amdgcn_mfma_f32_16x16x32_f16(a1, b[nt], acc[1][nt], 0, 0, 0);
    }
    if (kc + 1 < KC) {
      a0 = a0n; a1 = a1n;
      #pragma unroll
      for (int nt = 0; nt < 7; ++nt) b[nt] = bn[nt];
    }
  }
  int cbase = wc * 7 * 16 + (lane & 15);
  #pragma unroll
  for (int nt = 0; nt < 7; ++nt) {
    int c = cbase + nt * 16;
    int o = c >> 1;
    bool isre = !(c & 1);
    if (o < HID) {
      _Float16* outp = Aout + (isre ? o : 208 + o);
      #pragma unroll
      for (int rt = 0; rt < 2; ++rt)
        #pragma unroll
        for (int q = 0; q < 4; ++q) {
          float v = acc[rt][nt][q];
          if (isre) v = fmaxf(v, 0.f);
          outp[(size_t)(wr * 32 + rt * 16 + g * 4 + q) * AST] = (_Float16)v;
        }
    }
  }
}

__global__ __launch_bounds__(512, 2) void k_mlp_mfma(
    const float2* __restrict__ Vcur, const float2* __restrict__ Z2,
    const _Float16* __restrict__ Bp,
    const float* __restrict__ W4re, const float* __restrict__ W4im,
    const float* __restrict__ b4re,
    float2* __restrict__ Vout) {
  int b = blockIdx.x;
  int tid = threadIdx.x;
  int wave = tid >> 6, lane = tid & 63;
  int wr = wave >> 2, wc = wave & 3;

  __shared__ _Float16 A0[64 * AST0];
  __shared__ _Float16 Abuf[2][64 * AST];
  __shared__ float2 Zs[64][16];
  __shared__ float2 Z2s[64][16];
  __shared__ float w4s[2][HID];
  __shared__ float stepv[64];
  __shared__ float scs[8];

  for (int idx = tid; idx < 1024; idx += 512) {
    ((float2*)Zs)[idx]  = Vcur[(size_t)b * 1024 + idx];
    ((float2*)Z2s)[idx] = Z2[(size_t)b * 1024 + idx];
  }
  for (int idx = tid; idx < HID; idx += 512) {
    w4s[0][idx] = W4re[idx];
    w4s[1][idx] = W4im[idx];
  }
  __syncthreads();

  for (int idx = tid; idx < 64 * AST0; idx += 512) {
    int m = idx / AST0, c = idx % AST0;
    float v;
    if (c < 64) {
      int f = c & 31;
      float2 z = (f < 16) ? Zs[m][f] : Z2s[m][f - 16];
      v = (c >= 32) ? z.y : z.x;
    } else v = (c == 64) ? 1.f : 0.f;
    A0[m * AST0 + c] = (_Float16)v;
  }
  for (int idx = tid; idx < 2 * 64 * 16; idx += 512) {
    int buf = idx >> 10, rem = idx & 1023, m = rem >> 4, p = rem & 15;
    int c = (p < 8) ? (200 + p) : (400 + p);
    Abuf[buf][m * AST + c] = (p == 7) ? (_Float16)1.f : (_Float16)0.f;
  }
  __syncthreads();

  do_gemm<AST0, B1_KC>(A0, Bp, &Abuf[0][0], wr, wc, lane);
  __syncthreads();
  do_gemm<AST, B23_KC>(&Abuf[0][0], Bp + B1_HALVES, &Abuf[1][0], wr, wc, lane);
  __syncthreads();
  do_gemm<AST, B23_KC>(&Abuf[1][0], Bp + B1_HALVES + B23_HALVES, &Abuf[0][0], wr, wc, lane);
  __syncthreads();

  {
    int m = tid >> 3, q = tid & 7;
    float acc = 0.f;
    for (int o = q; o < HID; o += 8) {
      float hr = (float)Abuf[0][m * AST + o];
      float hi = (float)Abuf[0][m * AST + 208 + o];
      acc += hr * w4s[0][o] - hi * w4s[1][o];
    }
    acc += __shfl_down(acc, 4, 8);
    acc += __shfl_down(acc, 2, 8);
    acc += __shfl_down(acc, 1, 8);
    if (q == 0) stepv[m] = acc + b4re[0];
  }
  __syncthreads();

  for (int idx = tid; idx < 1024; idx += 512) {
    int m = idx >> 4, f = idx & 15;
    float st = stepv[m];
    float2 z = Zs[m][f], z2 = Z2s[m][f];
    Zs[m][f] = make_float2(fmaf(st, z2.x, z.x), fmaf(st, z2.y, z.y));
  }
  __syncthreads();

  {
    const float2* vp = &Zs[wave * 8][0];
    float2 v0 = vp[lane * 2], v1 = vp[lane * 2 + 1];
    float p = v0.x * v0.x + v0.y * v0.y + v1.x * v1.x + v1.y * v1.y;
    p += __shfl_down(p, 32); p += __shfl_down(p, 16); p += __shfl_down(p, 8);
    p += __shfl_down(p, 4);  p += __shfl_down(p, 2);  p += __shfl_down(p, 1);
    if (lane == 0) scs[wave] = (p > PP) ? sqrtf(PP / p) : 1.f;
  }
  __syncthreads();
  for (int idx = tid; idx < 1024; idx += 512) {
    float sc = scs[idx >> 7];
    float2 v = ((float2*)Zs)[idx];
    Vout[(size_t)b * 1024 + idx] = make_float2(v.x * sc, v.y * sc);
  }
}

// ---------------- launch ----------------
extern "C" void kernel_launch(void* const* d_in, const int* in_sizes, int n_in,
                              void* d_out, int out_size, void* d_ws, size_t ws_size,
                              hipStream_t stream) {
  const float* Hre  = (const float*)d_in[0];
  const float* Him  = (const float*)d_in[1];
  const float* Vre  = (const float*)d_in[2];
  const float* Vim  = (const float*)d_in[3];
  const float* w    = (const float*)d_in[4];
  const float* W1re = (const float*)d_in[5];
  const float* W1im = (const float*)d_in[6];
  const float* b1re = (const float*)d_in[7];
  const float* b1im = (const float*)d_in[8];
  const float* W2re = (const float*)d_in[9];
  const float* W2im = (const float*)d_in[10];
  const float* b2re = (const float*)d_in[11];
  const float* b2im = (const float*)d_in[12];
  const float* W3re = (const float*)d_in[13];
  const float* W3im = (const float*)d_in[14];
  const float* b3re = (const float*)d_in[15];
  const float* b3im = (const float*)d_in[16];
  const float* W4re = (const float*)d_in[17];
  const float* W4im = (const float*)d_in[18];
  const float* b4re = (const float*)d_in[19];

  const size_t NV = (size_t)NS * BS * UU * NT * DD;   // 229376
  const size_t NB = (size_t)NS * BS * UU;             // 14336
  float2* Vcur = (float2*)d_ws;
  float2* Z2b  = Vcur + NV;
  float2* Yb   = Z2b + NV;
  float2* IGb  = Yb + NB * 8;
  float2* Gsb  = IGb + NB * 4;
  float2* Tdb  = Gsb + NB * 10;
  float2* HV2b = Tdb + NB * 10;
  _Float16* Bpack = (_Float16*)(HV2b + NB * 8);

  k_pack<<<609, 256, 0, stream>>>(W1re, W1im, b1re, b1im, W2re, W2im, b2re, b2im,
                                  W3re, W3im, b3re, b3im, Bpack);
  k_norm0<<<NS * BS, 128, 0, stream>>>(Vre, Vim, Vcur);
  for (int it = 0; it < 3; ++it) {
    k_hv<<<NS * BS, 512, 0, stream>>>(Hre, Him, Vcur, Gsb, Tdb, HV2b);
    k_solve<<<112, 256, 0, stream>>>(Gsb, Tdb, HV2b, Yb, IGb);
    k_stage2<<<NS * BS, 256, 0, stream>>>(Hre, Him, Vcur, Yb, IGb, w, Z2b);
    float2* vout = (it == 2) ? (float2*)d_out : Vcur;
    k_mlp_mfma<<<NS * BS / 8, 512, 0, stream>>>(Vcur, Z2b,
        Bpack + (size_t)it * BITER_HALVES,
        W4re + it * HID, W4im + it * HID, b4re + it, vout);
  }
}